// Round 15
// baseline (29994.241 us; speedup 1.0000x reference)
//
#include <hip/hip_runtime.h>
#include <cstddef>

#define DEV __device__ __forceinline__

// ---- dims: B=16 S=256 IN_DIM=264 H=512 4H=2048 XI=471 N=256 M=64 R=4 OUT=256
constexpr int S_ = 256;
constexpr int NB = 256;
constexpr int NT = 256;

// R14 post-mortem: dur ~= FETCH/586GB/s (R10/R11/R14 all show the same ~580GB/s
// effective L2-fill ceiling) -> weight-fetch bound; per-XCD demand 10.2MB/step
// vs 4MB L2 forces re-fetch every step. R15 = R14 + bf16-packed Wx||Wh
// (k-pair packed u32, uint4 load = 4 cols x 2 k): gates weight bytes halved,
// per-XCD gates footprint 4.2MB ~= L2 capacity. Everything else identical.

// per-batch region offsets (floats), stride PB, base ws + b*PB
constexpr size_t bH    = 0;       // 2x512 h ping-pong [agent]
constexpr size_t bC    = 1024;    // 512 LSTM c [private: block ci=j/32]
constexpr size_t bXI   = 1536;    // 512 (471 used) [agent]
constexpr size_t bKNR  = 2048;    // 256 [agent]
constexpr size_t bALC  = 2304;    // 256 [agent]
constexpr size_t bCW   = 2560;    // 256 [agent]
constexpr size_t bWW   = 2816;    // 256 [agent]
constexpr size_t bNRM  = 3072;    // 256 [agent]
constexpr size_t bUSG  = 3328;    // 256 [private: ctrl block]
constexpr size_t bRV   = 3584;    // 256 [agent]
constexpr size_t bYH   = 3840;    // 256 [agent]
constexpr size_t bSCL  = 4096;    // 32  [agent]
constexpr size_t bPI   = 4128;    // 32  [agent]
constexpr size_t bERS  = 4160;    // 64  [agent]
constexpr size_t bWVC  = 4224;    // 64  [agent]
constexpr size_t bPRC  = 4288;    // 2x256 [agent]
constexpr size_t bWR   = 4800;    // 4x256 [agent]
constexpr size_t bFWD  = 5824;    // 4x256 [agent]
constexpr size_t bBWDP = 6848;    // 4 slots x 4 heads x 256 [agent zero + dev atomicAdd]
constexpr size_t bFLG  = 10944;   // 16 crew flags x 32 (1/128B line)
constexpr size_t bMEM  = 11456;   // 256x64 [agent]
constexpr size_t bLNK  = 27840;   // 256x256 [private: block ci owns rows 16ci..]
constexpr size_t PB    = 93376;
constexpr size_t OFF_W2 = PB*16;            // bf16-packed Wx||Wh: 516 kp x 2048 cols (u32 each)
constexpr size_t NW2    = 516*2048;         // 1,056,768 u32
constexpr size_t WS_TOTAL = OFF_W2 + NW2;   // ~10.2 MB

typedef unsigned long long u64_;
union F2U { u64_ u; float2 f; };
DEV float2 ld2_agt(const float* p){ F2U c; c.u=__hip_atomic_load((const u64_*)p,__ATOMIC_RELAXED,__HIP_MEMORY_SCOPE_AGENT); return c.f; }
DEV void   st2_agt(float* p, float2 v){ F2U c; c.f=v; __hip_atomic_store((u64_*)p,c.u,__ATOMIC_RELAXED,__HIP_MEMORY_SCOPE_AGENT); }
DEV float  ld_agt(const float* p){ return __hip_atomic_load((float*)p,__ATOMIC_RELAXED,__HIP_MEMORY_SCOPE_AGENT); }
DEV void   st_agt(float* p,float v){ __hip_atomic_store(p,v,__ATOMIC_RELAXED,__HIP_MEMORY_SCOPE_AGENT); }

DEV float sigm(float x){ return 1.0f/(1.0f+expf(-x)); }
DEV float oneplus_(float x){ float sp = (x>20.0f)? x : log1pf(expf(x)); return 1.0f+sp; }

DEV float bl16_lo(unsigned u){ return __uint_as_float(u<<16); }
DEV float bl16_hi(unsigned u){ return __uint_as_float(u & 0xffff0000u); }

DEV float wredsum(float v){
  #pragma unroll
  for (int o=32;o>0;o>>=1) v += __shfl_xor(v,o);
  return v;
}
DEV float hredsum32(float v){
  #pragma unroll
  for (int o=16;o>0;o>>=1) v += __shfl_xor(v,o);
  return v;
}
DEV float wredmax(float v){
  #pragma unroll
  for (int o=32;o>0;o>>=1) v = fmaxf(v,__shfl_xor(v,o));
  return v;
}
DEV float bredsum(float v, float* red){
  v = wredsum(v);
  if ((threadIdx.x&63)==0) red[threadIdx.x>>6]=v;
  __syncthreads();
  float r = red[0]+red[1]+red[2]+red[3];
  __syncthreads();
  return r;
}
DEV float bredmax(float v, float* red){
  v = wredmax(v);
  if ((threadIdx.x&63)==0) red[threadIdx.x>>6]=v;
  __syncthreads();
  float r = fmaxf(fmaxf(red[0],red[1]),fmaxf(red[2],red[3]));
  __syncthreads();
  return r;
}

// crew barrier, single-round busy spin (R14)
DEV void cbar(float* wsb, unsigned ep, int ci){
  unsigned* flg = (unsigned*)(wsb + bFLG);
  __syncthreads();
  if (threadIdx.x < 64){
    if (threadIdx.x == 0)
      __hip_atomic_store(flg + (size_t)ci*32, ep, __ATOMIC_RELAXED, __HIP_MEMORY_SCOPE_AGENT);
    const int l = threadIdx.x;
    bool ok;
    do {
      unsigned v = (l<16) ? __hip_atomic_load(flg + (size_t)l*32,
                      __ATOMIC_RELAXED, __HIP_MEMORY_SCOPE_AGENT) : ep;
      ok = __all(v >= ep);
    } while (!ok);
  }
  __syncthreads();
}

__global__ void k_zero(float* __restrict__ ws){
  size_t i = (size_t)blockIdx.x*blockDim.x + threadIdx.x;
  size_t st = (size_t)gridDim.x*blockDim.x;
  for (; i<PB*16; i+=st) ws[i]=0.0f;
}

// pack Wx (520x2048) || Wh (512x2048) into bf16 k-pairs: w2[kp*2048+col]
__global__ void k_conv(const float* __restrict__ Wx, const float* __restrict__ Wh,
                       unsigned* __restrict__ w2){
  size_t idx = (size_t)blockIdx.x*blockDim.x + threadIdx.x;
  if (idx >= NW2) return;
  int kp = (int)(idx >> 11), col = (int)(idx & 2047);
  int k0 = kp<<1, k1 = k0+1;
  float a = (k0<520) ? Wx[(size_t)k0*2048+col] : Wh[(size_t)(k0-520)*2048+col];
  float b = (k1<520) ? Wx[(size_t)k1*2048+col] : Wh[(size_t)(k1-520)*2048+col];
  unsigned ua = __float_as_uint(a), ub = __float_as_uint(b);
  ua = (ua + 0x7fffu + ((ua>>16)&1u)) >> 16;       // RNE to bf16
  ub = (ub + 0x7fffu + ((ub>>16)&1u)) >> 16;
  w2[idx] = (ub<<16) | ua;
}

__global__ __launch_bounds__(NT, 2) void k_dnc(
    const float* __restrict__ xin, const float* __restrict__ Wx,
    const float* __restrict__ Wh,  const float* __restrict__ bl,
    const float* __restrict__ Wxi, const float* __restrict__ bxi,
    const float* __restrict__ Wy,  const float* __restrict__ Wr,
    const float* __restrict__ by,  float* __restrict__ out,
    float* __restrict__ ws)
{
  __shared__ float smem[14336];   // 57 KB
  const int tid  = threadIdx.x;
  const int bid  = blockIdx.x;
  const int lane = tid & 63, wv = tid >> 6;
  // crew mapping: XCD x = bid%8; q = bid/8; s = q&1; ci = q>>1; batch = x+8s
  const int x  = bid & 7;
  const int q  = bid >> 3;
  const int s  = q & 1;
  const int ci = q >> 1;
  const int b  = x + (s<<3);
  float* wsb = ws + (size_t)b*PB;
  const unsigned* gW2 = (const unsigned*)(ws + OFF_W2);
  unsigned ep = 0;

  for (int t=0; t<S_; ++t){
    // ================= A: gates GEMM (bf16-packed, pipelined) + LSTM + y(t-1) =================
    {
      float* sact = smem;          // 1032 (pad 1040)
      float* sred = smem + 1040;   // 8x128
      float* gall = smem + 2064;   // 128
      float* ysum = smem + 2192;   // 256
      const float* hrd = wsb + bH + (size_t)(t&1)*512;
      float* hwr = wsb + bH + (size_t)((t+1)&1)*512;
      for (int e=tid; e<1032; e+=NT){
        float v;
        if (e < 264)      v = xin[((size_t)(b*256+t))*264 + e];
        else if (e < 520) v = ld_agt(wsb + bRV + (e-264));
        else              v = ld_agt(hrd + (e-520));
        sact[e] = v;
      }
      __syncthreads();
      if (t > 0){  // y(t-1) = YH + rv(t-1)@Wr ; rv staged in sact[264..519]
        int ks2 = tid>>4, cc = tid&15;
        int yc = (ci<<4) + cc;
        float a = 0.f;
        const float* wp = Wr + (size_t)(ks2*16)*256 + yc;
        const float* rp = sact + 264 + ks2*16;
        #pragma unroll
        for (int k=0;k<16;++k) a = fmaf(rp[k], wp[(size_t)k*256], a);
        ysum[ks2*16 + cc] = a;
        __syncthreads();
        if (tid < 16){
          float sm = 0.f;
          #pragma unroll
          for (int p=0;p<16;++p) sm += ysum[p*16 + tid];
          int yc2 = (ci<<4) + tid;
          out[((size_t)(b*256 + (t-1)))*256 + yc2] = ld_agt(wsb+bYH+yc2) + sm;
        }
        __syncthreads();
      }
      // gates GEMM: 128 cols, kp=516 pairs, 8-way ksplit, SW-pipelined uint4 prefetch
      {
        const int colq = tid & 31;
        const int ksA  = tid >> 5;
        const int g    = colq >> 3;
        const int col  = (g<<9) + (ci<<5) + ((colq&7)<<2);
        float4 acc; acc.x=0.f; acc.y=0.f; acc.z=0.f; acc.w=0.f;
        // kp split: ksA<4 -> 65 pairs (Wx rows), else 64 pairs (Wh rows)
        int kp0, kn;
        if (ksA < 4){ kp0 = ksA*65;        kn = 65; }
        else        { kp0 = 260+(ksA-4)*64; kn = 64; }
        const uint4* wp = (const uint4*)(gW2 + (size_t)kp0*2048 + col);
        const float* xp = sact + (kp0<<1);
        const int nch = (kn+7)>>3;
        uint4 buf[8];
        #pragma unroll
        for (int i=0;i<8;++i){
          int kk = (i<kn)? i : kn-1;
          buf[i] = wp[(size_t)kk*512];
        }
        for (int c=0; c<nch; ++c){
          uint4 nbuf[8];
          int nb0 = (c+1)<<3;
          #pragma unroll
          for (int i=0;i<8;++i){
            int kk = nb0+i; kk = (kk<kn)? kk : kn-1;
            nbuf[i] = wp[(size_t)kk*512];
          }
          int kb = c<<3;
          #pragma unroll
          for (int i=0;i<8;++i){
            bool val = (kb+i) < kn;
            float x0 = val ? xp[((kb+i)<<1)]   : 0.f;
            float x1 = val ? xp[((kb+i)<<1)+1] : 0.f;
            acc.x = fmaf(bl16_lo(buf[i].x), x0, fmaf(bl16_hi(buf[i].x), x1, acc.x));
            acc.y = fmaf(bl16_lo(buf[i].y), x0, fmaf(bl16_hi(buf[i].y), x1, acc.y));
            acc.z = fmaf(bl16_lo(buf[i].z), x0, fmaf(bl16_hi(buf[i].z), x1, acc.z));
            acc.w = fmaf(bl16_lo(buf[i].w), x0, fmaf(bl16_hi(buf[i].w), x1, acc.w));
          }
          #pragma unroll
          for (int i=0;i<8;++i) buf[i]=nbuf[i];
        }
        *(float4*)(sred + ksA*128 + (colq<<2)) = acc;
      }
      __syncthreads();
      if (tid < 128){
        int gg = tid>>5, cc = (ci<<5) + (tid&31);
        float sm = bl[(gg<<9)+cc];
        #pragma unroll
        for (int p=0;p<8;++p) sm += sred[(p<<7) + tid];
        gall[tid] = sm;
      }
      __syncthreads();
      if (tid < 32){
        int j = (ci<<5) + tid;
        float gi=gall[tid], gf=gall[32+tid], gg2=gall[64+tid], go=gall[96+tid];
        float co = wsb[bC + j];          // private (same CU every step)
        float cn = sigm(gf)*co + sigm(gi)*tanhf(gg2);
        float hn = sigm(go)*tanhf(cn);
        wsb[bC + j] = cn;
        st_agt(hwr + j, hn);
      }
    }
    ep++; cbar(wsb, ep, ci);

    // ================= B: xi = h@Wxi + bxi ; YH = h@Wy + by =================
    {
      float* shh = smem;         // 512
      float* sp  = smem + 512;   // 8x30
      float* syh = smem + 768;   // 16x16
      const float* hcur = wsb + bH + (size_t)((t+1)&1)*512;
      for (int e=tid; e<512; e+=NT) shh[e] = ld_agt(hcur + e);
      __syncthreads();
      const int nc = (ci<15) ? 30 : 21;
      if (tid < 240){
        int ks = tid/30, cc = tid%30;
        if (cc < nc){
          int col = ci*30 + cc;
          float a = 0.f;
          const float* wp = Wxi + (size_t)(ks*64)*471 + col;
          const float* hp = shh + ks*64;
          #pragma unroll 8
          for (int k=0;k<64;++k) a = fmaf(hp[k], wp[(size_t)k*471], a);
          sp[ks*30 + cc] = a;
        }
      }
      {
        int ks = tid>>4, cc = tid&15;
        int col = (ci<<4) + cc;
        float a = 0.f;
        const float* wp = Wy + (size_t)(ks*32)*256 + col;
        const float* hp = shh + ks*32;
        #pragma unroll 8
        for (int k=0;k<32;++k) a = fmaf(hp[k], wp[(size_t)k*256], a);
        syh[ks*16 + cc] = a;
      }
      __syncthreads();
      if (tid < nc){
        float sm = bxi[ci*30 + tid];
        #pragma unroll
        for (int p=0;p<8;++p) sm += sp[p*30 + tid];
        st_agt(wsb + bXI + ci*30 + tid, sm);
      }
      if (tid < 16){
        float sm = by[(ci<<4) + tid];
        #pragma unroll
        for (int p=0;p<16;++p) sm += syh[p*16 + tid];
        st_agt(wsb + bYH + (ci<<4) + tid, sm);
      }
    }
    ep++; cbar(wsb, ep, ci);

    // ================= C: ctrl(ci0) | content(ci1) | zero BWDP(ci2) =================
    if (ci == 0){
      float* xv = smem; float* uu = smem+512; float* sa = smem+768;
      float* sb = smem+1024; float* red = smem+1280;
      if (tid < 240){
        float2 v = ld2_agt(wsb + bXI + (tid<<1));
        xv[tid<<1]=v.x; xv[(tid<<1)+1]=v.y;
      }
      __syncthreads();
      int n = tid;
      float f0=sigm(xv[453]), f1=sigm(xv[454]), f2v=sigm(xv[455]), f3=sigm(xv[456]);
      const float* wrb = wsb + bWR;
      float psi=(1.f-f0*ld_agt(wrb+n))*(1.f-f1*ld_agt(wrb+256+n))
               *(1.f-f2v*ld_agt(wrb+512+n))*(1.f-f3*ld_agt(wrb+768+n));
      float uo=wsb[bUSG+n];
      float wwp=ld_agt(wsb+bWW+n);
      float un=(uo+wwp-uo*wwp)*psi;
      uu[n]=un; wsb[bUSG+n]=un;
      __syncthreads();
      int rk=0;
      #pragma unroll 8
      for (int j=0;j<256;++j){
        float uj=uu[j];
        rk += (uj<un)||(uj==un && j<n);
      }
      sa[rk]=un;
      __syncthreads();
      float* cur=sa; float* nxt=sb;
      for (int off=1;off<256;off<<=1){
        float v=cur[n]; if (n>=off) v*=cur[n-off];
        nxt[n]=v;
        __syncthreads();
        float* tmp=cur; cur=nxt; nxt=tmp;
      }
      float pe = rk ? cur[rk-1] : 1.f;
      float al = (1.f-un)*pe;
      st_agt(wsb+bALC+n, al);
      float sumA = bredsum(al, red);
      if (tid==0){
        st_agt(wsb+bSCL+0, sigm(xv[457]));
        st_agt(wsb+bSCL+1, sigm(xv[458]));
        st_agt(wsb+bSCL+2, sumA);
      }
      {
        int r=tid>>6, m=tid&63;
        float kv=xv[(r<<6)+m];
        float s2=wredsum(kv*kv);
        float br=oneplus_(xv[256+r]);
        st_agt(wsb+bKNR+tid, kv*br/(sqrtf(s2)+1e-6f));
      }
      if (tid<4){
        float p0=xv[459+tid*3], p1=xv[460+tid*3], p2=xv[461+tid*3];
        float mx=fmaxf(p0,fmaxf(p1,p2));
        float e0=expf(p0-mx), e1=expf(p1-mx), e2=expf(p2-mx);
        float sm=e0+e1+e2;
        st_agt(wsb+bPI+tid*3+0, e0/sm);
        st_agt(wsb+bPI+tid*3+1, e1/sm);
        st_agt(wsb+bPI+tid*3+2, e2/sm);
      }
      if (tid<64){
        st_agt(wsb+bERS+tid, sigm(xv[325+tid]));
        st_agt(wsb+bWVC+tid, xv[389+tid]);
      }
    } else if (ci == 1){
      float* knw=smem; float* sims=smem+64; float* red=smem+320;
      const int half = lane>>5, l32 = lane&31;
      if (wv==0){
        float kv=ld_agt(wsb+bXI+260+lane);
        float s2=wredsum(kv*kv);
        float bw_=oneplus_(ld_agt(wsb+bXI+324));
        knw[lane]=kv*bw_/(sqrtf(s2)+1e-6f);
      }
      __syncthreads();
      const float* memb=wsb+bMEM;
      for (int i2=0;i2<32;++i2){
        int n=(wv<<6)+(i2<<1)+half;
        float2 v=ld2_agt(memb+(n<<6)+(l32<<1));
        float d=hredsum32(v.x*knw[l32<<1]+v.y*knw[(l32<<1)+1]);
        if (l32==0) sims[n]=d/(sqrtf(ld_agt(wsb+bNRM+n))+1e-6f);
      }
      __syncthreads();
      float sv=sims[tid];
      float mx=bredmax(sv,red); float e=expf(sv-mx); float sm=bredsum(e,red);
      st_agt(wsb+bCW+tid, e/sm);
    } else if (ci == 2){
      for (int e=tid;e<4096;e+=NT) st_agt(wsb+bBWDP+e, 0.f);
    }
    ep++; cbar(wsb, ep, ci);

    // ================= D: link rows 16ci.. + fwd/bwd partials + mem/nrm/prec =================
    {
      float* wwl   = smem;         // 256
      float* wrl   = smem + 256;   // 4x16
      float* fpart = smem + 320;   // 4wv x 4r x 16
      float* sscl  = smem + 576;   // 4
      const int ri = ci<<4;
      if (tid < 3) sscl[tid] = ld_agt(wsb+bSCL+tid);
      __syncthreads();
      float ga = sscl[0], gw = sscl[1], sA = sscl[2];
      float sww = gw*(ga*sA + (1.f-ga));
      int j = tid;
      float wj = gw*(ga*ld_agt(wsb+bALC+j) + (1.f-ga)*ld_agt(wsb+bCW+j));
      wwl[j] = wj;
      if (ci == 1) st_agt(wsb+bWW+j, wj);
      float pj = ld_agt(wsb+bPRC + (size_t)(t&1)*256 + j);
      if (ci == 0) st_agt(wsb+bPRC + (size_t)((t+1)&1)*256 + j, (1.f-sww)*pj + wj);
      const float* wrb = wsb + bWR;
      float wr0=ld_agt(wrb+j), wr1=ld_agt(wrb+256+j),
            wr2=ld_agt(wrb+512+j), wr3=ld_agt(wrb+768+j);
      if (tid < 64) wrl[(tid>>4)*16 + (tid&15)] = ld_agt(wrb + ((size_t)(tid>>4)<<8) + ri + (tid&15));
      __syncthreads();
      float b0=0.f,b1=0.f,b2=0.f,b3=0.f;
      float* lrow = wsb + bLNK + (size_t)ri*256;   // private, L1/L2-resident
      for (int il=0; il<16; ++il){
        int irow = ri + il;
        float Lo = lrow[il*256 + j];
        float wi = wwl[irow];
        float Ln = (1.f - wi - wj)*Lo + wi*pj;
        if (irow == j) Ln = 0.f;
        lrow[il*256 + j] = Ln;
        float s0=wredsum(Ln*wr0), s1=wredsum(Ln*wr1), s2=wredsum(Ln*wr2), s3=wredsum(Ln*wr3);
        if (lane==0){
          fpart[wv*64 + il]      = s0;
          fpart[wv*64 + 16 + il] = s1;
          fpart[wv*64 + 32 + il] = s2;
          fpart[wv*64 + 48 + il] = s3;
        }
        b0=fmaf(Ln, wrl[il],    b0);
        b1=fmaf(Ln, wrl[16+il], b1);
        b2=fmaf(Ln, wrl[32+il], b2);
        b3=fmaf(Ln, wrl[48+il], b3);
      }
      __syncthreads();
      if (tid < 64){
        int r = tid>>4, il = tid&15;
        float sm = fpart[r*16+il] + fpart[64+r*16+il] + fpart[128+r*16+il] + fpart[192+r*16+il];
        st_agt(wsb+bFWD + ((size_t)r<<8) + ri + il, sm);
      }
      float* slot = wsb + bBWDP + (size_t)(ci&3)*1024;   // 4-way contention only
      atomicAdd(&slot[j], b0);      atomicAdd(&slot[256+j], b1);
      atomicAdd(&slot[512+j], b2);  atomicAdd(&slot[768+j], b3);
      // mem update rows ri..ri+15
      {
        int row2 = tid>>5, c2 = tid&31;
        float2 er  = ld2_agt(wsb+bERS + (c2<<1));
        float2 wv2 = ld2_agt(wsb+bWVC + (c2<<1));
        #pragma unroll
        for (int it=0; it<2; ++it){
          int row = ri + row2 + it*8;
          float wwn = wwl[row];
          float2 v = ld2_agt(wsb+bMEM + ((size_t)row<<6) + (c2<<1));
          v.x = v.x*(1.f - wwn*er.x) + wwn*wv2.x;
          v.y = v.y*(1.f - wwn*er.y) + wwn*wv2.y;
          st2_agt(wsb+bMEM + ((size_t)row<<6) + (c2<<1), v);
          float s2 = hredsum32(v.x*v.x + v.y*v.y);
          if (c2==0) st_agt(wsb+bNRM+row, s2);
        }
      }
    }
    ep++; cbar(wsb, ep, ci);

    // ================= E: read heads (ci<4: head r=ci) =================
    if (ci < 4){
      int r = ci;
      float* knl=smem; float* sims=smem+64; float* wrs=smem+320;
      float* part=smem+576; float* red=smem+832;
      if (wv==0) knl[lane]=ld_agt(wsb+bKNR+(r<<6)+lane);
      __syncthreads();
      const float* memb = wsb + bMEM;
      {
        int row2 = tid>>5, c2 = tid&31;
        for (int it=0; it<32; ++it){
          int n = row2 + it*8;
          float2 v = ld2_agt(memb + ((size_t)n<<6) + (c2<<1));
          float d = hredsum32(v.x*knl[c2<<1] + v.y*knl[(c2<<1)+1]);
          if (c2==0) sims[n] = d/(sqrtf(ld_agt(wsb+bNRM+n))+1e-6f);
        }
      }
      __syncthreads();
      float sv=sims[tid];
      float mx=bredmax(sv,red); float e=expf(sv-mx); float sm=bredsum(e,red);
      float cr=e/sm;
      float p0=ld_agt(wsb+bPI+r*3), p1=ld_agt(wsb+bPI+r*3+1), p2=ld_agt(wsb+bPI+r*3+2);
      float bwv = ld_agt(wsb+bBWDP + ((size_t)r<<8) + tid)
                + ld_agt(wsb+bBWDP + 1024 + ((size_t)r<<8) + tid)
                + ld_agt(wsb+bBWDP + 2048 + ((size_t)r<<8) + tid)
                + ld_agt(wsb+bBWDP + 3072 + ((size_t)r<<8) + tid);
      float wr = p0*bwv + p1*cr + p2*ld_agt(wsb+bFWD+((size_t)r<<8)+tid);
      st_agt(wsb+bWR+((size_t)r<<8)+tid, wr);
      wrs[tid]=wr;
      __syncthreads();
      {
        int m = tid&63, ksn = tid>>6;
        float a=0.f;
        #pragma unroll 8
        for (int n0=0;n0<64;++n0){
          int n = (ksn<<6)+n0;
          a = fmaf(wrs[n], ld_agt(memb + ((size_t)n<<6) + m), a);
        }
        part[(ksn<<6)+m]=a;
      }
      __syncthreads();
      if (tid<64)
        st_agt(wsb+bRV+(r<<6)+tid, part[tid]+part[64+tid]+part[128+tid]+part[192+tid]);
    }
    ep++; cbar(wsb, ep, ci);
  }

  // ---- epilogue: y(255) = YH + rv(255) @ Wr ----
  {
    float* srv  = smem;        // 256
    float* ysum = smem + 256;  // 256
    for (int e=tid;e<256;e+=NT) srv[e]=ld_agt(wsb+bRV+e);
    __syncthreads();
    int ks2 = tid>>4, cc = tid&15;
    int yc = (ci<<4) + cc;
    float a = 0.f;
    const float* wp = Wr + (size_t)(ks2*16)*256 + yc;
    const float* rp = srv + ks2*16;
    #pragma unroll
    for (int k=0;k<16;++k) a = fmaf(rp[k], wp[(size_t)k*256], a);
    ysum[ks2*16 + cc] = a;
    __syncthreads();
    if (tid < 16){
      float sm = 0.f;
      #pragma unroll
      for (int p=0;p<16;++p) sm += ysum[p*16 + tid];
      int yc2 = (ci<<4) + tid;
      out[((size_t)(b*256 + 255))*256 + yc2] = ld_agt(wsb+bYH+yc2) + sm;
    }
  }
}

extern "C" void kernel_launch(void* const* d_in, const int* in_sizes, int n_in,
                              void* d_out, int out_size, void* d_ws, size_t ws_size,
                              hipStream_t stream) {
  (void)in_sizes; (void)out_size;
  if (n_in < 9) return;
  const float* xin = (const float*)d_in[0];
  const float* Wx  = (const float*)d_in[1];
  const float* Wh  = (const float*)d_in[2];
  const float* bl  = (const float*)d_in[3];
  const float* Wxi = (const float*)d_in[4];
  const float* bxi = (const float*)d_in[5];
  const float* Wy  = (const float*)d_in[6];
  const float* Wr  = (const float*)d_in[7];
  const float* by  = (const float*)d_in[8];
  float* out = (float*)d_out;
  float* ws  = (float*)d_ws;
  if (ws_size < WS_TOTAL*sizeof(float)) return;

  hipLaunchKernelGGL(k_zero, dim3(512), dim3(256), 0, stream, ws);
  hipLaunchKernelGGL(k_conv, dim3((NW2+255)/256), dim3(256), 0, stream,
                     Wx, Wh, (unsigned*)(ws + OFF_W2));
  hipLaunchKernelGGL(k_dnc, dim3(NB), dim3(NT), 0, stream,
                     xin, Wx, Wh, bl, Wxi, bxi, Wy, Wr, by, out, ws);
}

// Round 16
// 23363.190 us; speedup vs baseline: 1.2838x; 1.2838x over previous
//
#include <hip/hip_runtime.h>
#include <cstddef>

#define DEV __device__ __forceinline__

// ---- dims: B=16 S=256 IN_DIM=264 H=512 4H=2048 XI=471 N=256 M=64 R=4 OUT=256
constexpr int S_ = 256;
constexpr int NB = 256;
constexpr int NT = 256;

// R15 post-mortem: per-step time 90-120us invariant to bytes/hops/protocol/NT
// -> last consistent explanation: POLL STORM. ~240 blocks spin in cbar at
// ~700cyc/iter x 16 flag loads = ~13G line-loads/s ~= 845 GB/s parasitic LLC
// traffic, throttling the productive phase (observed ~586 GB/s ceiling).
// Tiny s_sleep(1..4) doesn't change iteration period -> why all sleep variants
// tied. R16 = R14 verbatim, ONE change: cbar polls 8 fast iterations then
// backs off with s_sleep(64) (~4096cyc) -> ~6x less poll traffic, ~0.9us mean
// extra detection latency per barrier.

// per-batch region offsets (floats), stride PB, base ws + b*PB
constexpr size_t bH    = 0;       // 2x512 h ping-pong [agent]
constexpr size_t bC    = 1024;    // 512 LSTM c [private: block ci=j/32]
constexpr size_t bXI   = 1536;    // 512 (471 used) [agent]
constexpr size_t bKNR  = 2048;    // 256 [agent]
constexpr size_t bALC  = 2304;    // 256 [agent]
constexpr size_t bCW   = 2560;    // 256 [agent]
constexpr size_t bWW   = 2816;    // 256 [agent]
constexpr size_t bNRM  = 3072;    // 256 [agent]
constexpr size_t bUSG  = 3328;    // 256 [private: ctrl block]
constexpr size_t bRV   = 3584;    // 256 [agent]
constexpr size_t bYH   = 3840;    // 256 [agent]
constexpr size_t bSCL  = 4096;    // 32  [agent]
constexpr size_t bPI   = 4128;    // 32  [agent]
constexpr size_t bERS  = 4160;    // 64  [agent]
constexpr size_t bWVC  = 4224;    // 64  [agent]
constexpr size_t bPRC  = 4288;    // 2x256 [agent]
constexpr size_t bWR   = 4800;    // 4x256 [agent]
constexpr size_t bFWD  = 5824;    // 4x256 [agent]
constexpr size_t bBWDP = 6848;    // 4 slots x 4 heads x 256 [agent zero + dev atomicAdd]
constexpr size_t bFLG  = 10944;   // 16 crew flags x 32 (1/128B line)
constexpr size_t bMEM  = 11456;   // 256x64 [agent]
constexpr size_t bLNK  = 27840;   // 256x256 [private: block ci owns rows 16ci..]
constexpr size_t PB    = 93376;
constexpr size_t WS_TOTAL = PB*16;   // ~5.98 MB

typedef unsigned long long u64_;
union F2U { u64_ u; float2 f; };
DEV float2 ld2_agt(const float* p){ F2U c; c.u=__hip_atomic_load((const u64_*)p,__ATOMIC_RELAXED,__HIP_MEMORY_SCOPE_AGENT); return c.f; }
DEV void   st2_agt(float* p, float2 v){ F2U c; c.f=v; __hip_atomic_store((u64_*)p,c.u,__ATOMIC_RELAXED,__HIP_MEMORY_SCOPE_AGENT); }
DEV float  ld_agt(const float* p){ return __hip_atomic_load((float*)p,__ATOMIC_RELAXED,__HIP_MEMORY_SCOPE_AGENT); }
DEV void   st_agt(float* p,float v){ __hip_atomic_store(p,v,__ATOMIC_RELAXED,__HIP_MEMORY_SCOPE_AGENT); }

DEV float sigm(float x){ return 1.0f/(1.0f+expf(-x)); }
DEV float oneplus_(float x){ float sp = (x>20.0f)? x : log1pf(expf(x)); return 1.0f+sp; }

DEV float wredsum(float v){
  #pragma unroll
  for (int o=32;o>0;o>>=1) v += __shfl_xor(v,o);
  return v;
}
DEV float hredsum32(float v){
  #pragma unroll
  for (int o=16;o>0;o>>=1) v += __shfl_xor(v,o);
  return v;
}
DEV float wredmax(float v){
  #pragma unroll
  for (int o=32;o>0;o>>=1) v = fmaxf(v,__shfl_xor(v,o));
  return v;
}
DEV float bredsum(float v, float* red){
  v = wredsum(v);
  if ((threadIdx.x&63)==0) red[threadIdx.x>>6]=v;
  __syncthreads();
  float r = red[0]+red[1]+red[2]+red[3];
  __syncthreads();
  return r;
}
DEV float bredmax(float v, float* red){
  v = wredmax(v);
  if ((threadIdx.x&63)==0) red[threadIdx.x>>6]=v;
  __syncthreads();
  float r = fmaxf(fmaxf(red[0],red[1]),fmaxf(red[2],red[3]));
  __syncthreads();
  return r;
}

// crew barrier, single-round. R16: 8 fast polls, then s_sleep(64) backoff
// (~4096cyc/iter) to kill the LLC poll storm while waiting.
DEV void cbar(float* wsb, unsigned ep, int ci){
  unsigned* flg = (unsigned*)(wsb + bFLG);
  __syncthreads();
  if (threadIdx.x < 64){
    if (threadIdx.x == 0)
      __hip_atomic_store(flg + (size_t)ci*32, ep, __ATOMIC_RELAXED, __HIP_MEMORY_SCOPE_AGENT);
    const int l = threadIdx.x;
    int spin = 0;
    bool ok;
    do {
      unsigned v = (l<16) ? __hip_atomic_load(flg + (size_t)l*32,
                      __ATOMIC_RELAXED, __HIP_MEMORY_SCOPE_AGENT) : ep;
      ok = __all(v >= ep);
      if (!ok && ++spin > 8) __builtin_amdgcn_s_sleep(64);
    } while (!ok);
  }
  __syncthreads();
}

__global__ void k_zero(float* __restrict__ ws){
  size_t i = (size_t)blockIdx.x*blockDim.x + threadIdx.x;
  size_t st = (size_t)gridDim.x*blockDim.x;
  for (; i<WS_TOTAL; i+=st) ws[i]=0.0f;
}

__global__ __launch_bounds__(NT, 2) void k_dnc(
    const float* __restrict__ xin, const float* __restrict__ Wx,
    const float* __restrict__ Wh,  const float* __restrict__ bl,
    const float* __restrict__ Wxi, const float* __restrict__ bxi,
    const float* __restrict__ Wy,  const float* __restrict__ Wr,
    const float* __restrict__ by,  float* __restrict__ out,
    float* __restrict__ ws)
{
  __shared__ float smem[14336];   // 57 KB
  const int tid  = threadIdx.x;
  const int bid  = blockIdx.x;
  const int lane = tid & 63, wv = tid >> 6;
  // crew mapping: XCD x = bid%8; q = bid/8; s = q&1; ci = q>>1; batch = x+8s
  const int x  = bid & 7;
  const int q  = bid >> 3;
  const int s  = q & 1;
  const int ci = q >> 1;
  const int b  = x + (s<<3);
  float* wsb = ws + (size_t)b*PB;
  unsigned ep = 0;

  for (int t=0; t<S_; ++t){
    // ================= A: gates GEMM (pipelined) + LSTM + y(t-1) =================
    {
      float* sact = smem;          // 1032 (pad 1040)
      float* sred = smem + 1040;   // 8x128
      float* gall = smem + 2064;   // 128
      float* ysum = smem + 2192;   // 256
      const float* hrd = wsb + bH + (size_t)(t&1)*512;
      float* hwr = wsb + bH + (size_t)((t+1)&1)*512;
      for (int e=tid; e<1032; e+=NT){
        float v;
        if (e < 264)      v = xin[((size_t)(b*256+t))*264 + e];
        else if (e < 520) v = ld_agt(wsb + bRV + (e-264));
        else              v = ld_agt(hrd + (e-520));
        sact[e] = v;
      }
      __syncthreads();
      if (t > 0){  // y(t-1) = YH + rv(t-1)@Wr ; rv staged in sact[264..519]
        int ks2 = tid>>4, cc = tid&15;
        int yc = (ci<<4) + cc;
        float a = 0.f;
        const float* wp = Wr + (size_t)(ks2*16)*256 + yc;
        const float* rp = sact + 264 + ks2*16;
        #pragma unroll
        for (int k=0;k<16;++k) a = fmaf(rp[k], wp[(size_t)k*256], a);
        ysum[ks2*16 + cc] = a;
        __syncthreads();
        if (tid < 16){
          float sm = 0.f;
          #pragma unroll
          for (int p=0;p<16;++p) sm += ysum[p*16 + tid];
          int yc2 = (ci<<4) + tid;
          out[((size_t)(b*256 + (t-1)))*256 + yc2] = ld_agt(wsb+bYH+yc2) + sm;
        }
        __syncthreads();
      }
      // gates GEMM: 128 cols, k=1032, 8-way ksplit, SW-pipelined prefetch
      {
        const int colq = tid & 31;
        const int ksA  = tid >> 5;
        const int g    = colq >> 3;
        const int col  = (g<<9) + (ci<<5) + ((colq&7)<<2);
        float4 acc; acc.x=0.f; acc.y=0.f; acc.z=0.f; acc.w=0.f;
        const float4* wp; const float* xp; int kn;
        if (ksA < 4){
          int k0 = ksA*130; kn = 130;
          wp = (const float4*)(Wx + (size_t)k0*2048 + col);
          xp = sact + k0;
        } else {
          int k0 = (ksA-4)*128; kn = 128;
          wp = (const float4*)(Wh + (size_t)k0*2048 + col);
          xp = sact + 520 + k0;
        }
        const int nch = (kn+7)>>3;
        float4 buf[8];
        #pragma unroll
        for (int i=0;i<8;++i){
          int kk = (i<kn)? i : kn-1;
          buf[i] = wp[(size_t)kk*512];
        }
        for (int c=0; c<nch; ++c){
          float4 nbuf[8];
          int nb0 = (c+1)<<3;
          #pragma unroll
          for (int i=0;i<8;++i){
            int kk = nb0+i; kk = (kk<kn)? kk : kn-1;
            nbuf[i] = wp[(size_t)kk*512];
          }
          int kb = c<<3;
          #pragma unroll
          for (int i=0;i<8;++i){
            float xv = (kb+i<kn)? xp[kb+i] : 0.f;
            acc.x=fmaf(buf[i].x,xv,acc.x); acc.y=fmaf(buf[i].y,xv,acc.y);
            acc.z=fmaf(buf[i].z,xv,acc.z); acc.w=fmaf(buf[i].w,xv,acc.w);
          }
          #pragma unroll
          for (int i=0;i<8;++i) buf[i]=nbuf[i];
        }
        *(float4*)(sred + ksA*128 + (colq<<2)) = acc;
      }
      __syncthreads();
      if (tid < 128){
        int gg = tid>>5, cc = (ci<<5) + (tid&31);
        float sm = bl[(gg<<9)+cc];
        #pragma unroll
        for (int p=0;p<8;++p) sm += sred[(p<<7) + tid];
        gall[tid] = sm;
      }
      __syncthreads();
      if (tid < 32){
        int j = (ci<<5) + tid;
        float gi=gall[tid], gf=gall[32+tid], gg2=gall[64+tid], go=gall[96+tid];
        float co = wsb[bC + j];          // private (same CU every step)
        float cn = sigm(gf)*co + sigm(gi)*tanhf(gg2);
        float hn = sigm(go)*tanhf(cn);
        wsb[bC + j] = cn;
        st_agt(hwr + j, hn);
      }
    }
    ep++; cbar(wsb, ep, ci);

    // ================= B: xi = h@Wxi + bxi ; YH = h@Wy + by =================
    {
      float* shh = smem;         // 512
      float* sp  = smem + 512;   // 8x30
      float* syh = smem + 768;   // 16x16
      const float* hcur = wsb + bH + (size_t)((t+1)&1)*512;
      for (int e=tid; e<512; e+=NT) shh[e] = ld_agt(hcur + e);
      __syncthreads();
      const int nc = (ci<15) ? 30 : 21;
      if (tid < 240){
        int ks = tid/30, cc = tid%30;
        if (cc < nc){
          int col = ci*30 + cc;
          float a = 0.f;
          const float* wp = Wxi + (size_t)(ks*64)*471 + col;
          const float* hp = shh + ks*64;
          #pragma unroll 8
          for (int k=0;k<64;++k) a = fmaf(hp[k], wp[(size_t)k*471], a);
          sp[ks*30 + cc] = a;
        }
      }
      {
        int ks = tid>>4, cc = tid&15;
        int col = (ci<<4) + cc;
        float a = 0.f;
        const float* wp = Wy + (size_t)(ks*32)*256 + col;
        const float* hp = shh + ks*32;
        #pragma unroll 8
        for (int k=0;k<32;++k) a = fmaf(hp[k], wp[(size_t)k*256], a);
        syh[ks*16 + cc] = a;
      }
      __syncthreads();
      if (tid < nc){
        float sm = bxi[ci*30 + tid];
        #pragma unroll
        for (int p=0;p<8;++p) sm += sp[p*30 + tid];
        st_agt(wsb + bXI + ci*30 + tid, sm);
      }
      if (tid < 16){
        float sm = by[(ci<<4) + tid];
        #pragma unroll
        for (int p=0;p<16;++p) sm += syh[p*16 + tid];
        st_agt(wsb + bYH + (ci<<4) + tid, sm);
      }
    }
    ep++; cbar(wsb, ep, ci);

    // ================= C: ctrl(ci0) | content(ci1) | zero BWDP(ci2) =================
    if (ci == 0){
      float* xv = smem; float* uu = smem+512; float* sa = smem+768;
      float* sb = smem+1024; float* red = smem+1280;
      if (tid < 240){
        float2 v = ld2_agt(wsb + bXI + (tid<<1));
        xv[tid<<1]=v.x; xv[(tid<<1)+1]=v.y;
      }
      __syncthreads();
      int n = tid;
      float f0=sigm(xv[453]), f1=sigm(xv[454]), f2v=sigm(xv[455]), f3=sigm(xv[456]);
      const float* wrb = wsb + bWR;
      float psi=(1.f-f0*ld_agt(wrb+n))*(1.f-f1*ld_agt(wrb+256+n))
               *(1.f-f2v*ld_agt(wrb+512+n))*(1.f-f3*ld_agt(wrb+768+n));
      float uo=wsb[bUSG+n];
      float wwp=ld_agt(wsb+bWW+n);
      float un=(uo+wwp-uo*wwp)*psi;
      uu[n]=un; wsb[bUSG+n]=un;
      __syncthreads();
      int rk=0;
      #pragma unroll 8
      for (int j=0;j<256;++j){
        float uj=uu[j];
        rk += (uj<un)||(uj==un && j<n);
      }
      sa[rk]=un;
      __syncthreads();
      float* cur=sa; float* nxt=sb;
      for (int off=1;off<256;off<<=1){
        float v=cur[n]; if (n>=off) v*=cur[n-off];
        nxt[n]=v;
        __syncthreads();
        float* tmp=cur; cur=nxt; nxt=tmp;
      }
      float pe = rk ? cur[rk-1] : 1.f;
      float al = (1.f-un)*pe;
      st_agt(wsb+bALC+n, al);
      float sumA = bredsum(al, red);
      if (tid==0){
        st_agt(wsb+bSCL+0, sigm(xv[457]));
        st_agt(wsb+bSCL+1, sigm(xv[458]));
        st_agt(wsb+bSCL+2, sumA);
      }
      {
        int r=tid>>6, m=tid&63;
        float kv=xv[(r<<6)+m];
        float s2=wredsum(kv*kv);
        float br=oneplus_(xv[256+r]);
        st_agt(wsb+bKNR+tid, kv*br/(sqrtf(s2)+1e-6f));
      }
      if (tid<4){
        float p0=xv[459+tid*3], p1=xv[460+tid*3], p2=xv[461+tid*3];
        float mx=fmaxf(p0,fmaxf(p1,p2));
        float e0=expf(p0-mx), e1=expf(p1-mx), e2=expf(p2-mx);
        float sm=e0+e1+e2;
        st_agt(wsb+bPI+tid*3+0, e0/sm);
        st_agt(wsb+bPI+tid*3+1, e1/sm);
        st_agt(wsb+bPI+tid*3+2, e2/sm);
      }
      if (tid<64){
        st_agt(wsb+bERS+tid, sigm(xv[325+tid]));
        st_agt(wsb+bWVC+tid, xv[389+tid]);
      }
    } else if (ci == 1){
      float* knw=smem; float* sims=smem+64; float* red=smem+320;
      const int half = lane>>5, l32 = lane&31;
      if (wv==0){
        float kv=ld_agt(wsb+bXI+260+lane);
        float s2=wredsum(kv*kv);
        float bw_=oneplus_(ld_agt(wsb+bXI+324));
        knw[lane]=kv*bw_/(sqrtf(s2)+1e-6f);
      }
      __syncthreads();
      const float* memb=wsb+bMEM;
      for (int i2=0;i2<32;++i2){
        int n=(wv<<6)+(i2<<1)+half;
        float2 v=ld2_agt(memb+(n<<6)+(l32<<1));
        float d=hredsum32(v.x*knw[l32<<1]+v.y*knw[(l32<<1)+1]);
        if (l32==0) sims[n]=d/(sqrtf(ld_agt(wsb+bNRM+n))+1e-6f);
      }
      __syncthreads();
      float sv=sims[tid];
      float mx=bredmax(sv,red); float e=expf(sv-mx); float sm=bredsum(e,red);
      st_agt(wsb+bCW+tid, e/sm);
    } else if (ci == 2){
      for (int e=tid;e<4096;e+=NT) st_agt(wsb+bBWDP+e, 0.f);
    }
    ep++; cbar(wsb, ep, ci);

    // ================= D: link rows 16ci.. + fwd/bwd partials + mem/nrm/prec =================
    {
      float* wwl   = smem;         // 256
      float* wrl   = smem + 256;   // 4x16
      float* fpart = smem + 320;   // 4wv x 4r x 16
      float* sscl  = smem + 576;   // 4
      const int ri = ci<<4;
      if (tid < 3) sscl[tid] = ld_agt(wsb+bSCL+tid);
      __syncthreads();
      float ga = sscl[0], gw = sscl[1], sA = sscl[2];
      float sww = gw*(ga*sA + (1.f-ga));
      int j = tid;
      float wj = gw*(ga*ld_agt(wsb+bALC+j) + (1.f-ga)*ld_agt(wsb+bCW+j));
      wwl[j] = wj;
      if (ci == 1) st_agt(wsb+bWW+j, wj);
      float pj = ld_agt(wsb+bPRC + (size_t)(t&1)*256 + j);
      if (ci == 0) st_agt(wsb+bPRC + (size_t)((t+1)&1)*256 + j, (1.f-sww)*pj + wj);
      const float* wrb = wsb + bWR;
      float wr0=ld_agt(wrb+j), wr1=ld_agt(wrb+256+j),
            wr2=ld_agt(wrb+512+j), wr3=ld_agt(wrb+768+j);
      if (tid < 64) wrl[(tid>>4)*16 + (tid&15)] = ld_agt(wrb + ((size_t)(tid>>4)<<8) + ri + (tid&15));
      __syncthreads();
      float b0=0.f,b1=0.f,b2=0.f,b3=0.f;
      float* lrow = wsb + bLNK + (size_t)ri*256;   // private, L1/L2-resident
      for (int il=0; il<16; ++il){
        int irow = ri + il;
        float Lo = lrow[il*256 + j];
        float wi = wwl[irow];
        float Ln = (1.f - wi - wj)*Lo + wi*pj;
        if (irow == j) Ln = 0.f;
        lrow[il*256 + j] = Ln;
        float s0=wredsum(Ln*wr0), s1=wredsum(Ln*wr1), s2=wredsum(Ln*wr2), s3=wredsum(Ln*wr3);
        if (lane==0){
          fpart[wv*64 + il]      = s0;
          fpart[wv*64 + 16 + il] = s1;
          fpart[wv*64 + 32 + il] = s2;
          fpart[wv*64 + 48 + il] = s3;
        }
        b0=fmaf(Ln, wrl[il],    b0);
        b1=fmaf(Ln, wrl[16+il], b1);
        b2=fmaf(Ln, wrl[32+il], b2);
        b3=fmaf(Ln, wrl[48+il], b3);
      }
      __syncthreads();
      if (tid < 64){
        int r = tid>>4, il = tid&15;
        float sm = fpart[r*16+il] + fpart[64+r*16+il] + fpart[128+r*16+il] + fpart[192+r*16+il];
        st_agt(wsb+bFWD + ((size_t)r<<8) + ri + il, sm);
      }
      float* slot = wsb + bBWDP + (size_t)(ci&3)*1024;   // 4-way contention only
      atomicAdd(&slot[j], b0);      atomicAdd(&slot[256+j], b1);
      atomicAdd(&slot[512+j], b2);  atomicAdd(&slot[768+j], b3);
      // mem update rows ri..ri+15
      {
        int row2 = tid>>5, c2 = tid&31;
        float2 er  = ld2_agt(wsb+bERS + (c2<<1));
        float2 wv2 = ld2_agt(wsb+bWVC + (c2<<1));
        #pragma unroll
        for (int it=0; it<2; ++it){
          int row = ri + row2 + it*8;
          float wwn = wwl[row];
          float2 v = ld2_agt(wsb+bMEM + ((size_t)row<<6) + (c2<<1));
          v.x = v.x*(1.f - wwn*er.x) + wwn*wv2.x;
          v.y = v.y*(1.f - wwn*er.y) + wwn*wv2.y;
          st2_agt(wsb+bMEM + ((size_t)row<<6) + (c2<<1), v);
          float s2 = hredsum32(v.x*v.x + v.y*v.y);
          if (c2==0) st_agt(wsb+bNRM+row, s2);
        }
      }
    }
    ep++; cbar(wsb, ep, ci);

    // ================= E: read heads (ci<4: head r=ci) =================
    if (ci < 4){
      int r = ci;
      float* knl=smem; float* sims=smem+64; float* wrs=smem+320;
      float* part=smem+576; float* red=smem+832;
      if (wv==0) knl[lane]=ld_agt(wsb+bKNR+(r<<6)+lane);
      __syncthreads();
      const float* memb = wsb + bMEM;
      {
        int row2 = tid>>5, c2 = tid&31;
        for (int it=0; it<32; ++it){
          int n = row2 + it*8;
          float2 v = ld2_agt(memb + ((size_t)n<<6) + (c2<<1));
          float d = hredsum32(v.x*knl[c2<<1] + v.y*knl[(c2<<1)+1]);
          if (c2==0) sims[n] = d/(sqrtf(ld_agt(wsb+bNRM+n))+1e-6f);
        }
      }
      __syncthreads();
      float sv=sims[tid];
      float mx=bredmax(sv,red); float e=expf(sv-mx); float sm=bredsum(e,red);
      float cr=e/sm;
      float p0=ld_agt(wsb+bPI+r*3), p1=ld_agt(wsb+bPI+r*3+1), p2=ld_agt(wsb+bPI+r*3+2);
      float bwv = ld_agt(wsb+bBWDP + ((size_t)r<<8) + tid)
                + ld_agt(wsb+bBWDP + 1024 + ((size_t)r<<8) + tid)
                + ld_agt(wsb+bBWDP + 2048 + ((size_t)r<<8) + tid)
                + ld_agt(wsb+bBWDP + 3072 + ((size_t)r<<8) + tid);
      float wr = p0*bwv + p1*cr + p2*ld_agt(wsb+bFWD+((size_t)r<<8)+tid);
      st_agt(wsb+bWR+((size_t)r<<8)+tid, wr);
      wrs[tid]=wr;
      __syncthreads();
      {
        int m = tid&63, ksn = tid>>6;
        float a=0.f;
        #pragma unroll 8
        for (int n0=0;n0<64;++n0){
          int n = (ksn<<6)+n0;
          a = fmaf(wrs[n], ld_agt(memb + ((size_t)n<<6) + m), a);
        }
        part[(ksn<<6)+m]=a;
      }
      __syncthreads();
      if (tid<64)
        st_agt(wsb+bRV+(r<<6)+tid, part[tid]+part[64+tid]+part[128+tid]+part[192+tid]);
    }
    ep++; cbar(wsb, ep, ci);
  }

  // ---- epilogue: y(255) = YH + rv(255) @ Wr ----
  {
    float* srv  = smem;        // 256
    float* ysum = smem + 256;  // 256
    for (int e=tid;e<256;e+=NT) srv[e]=ld_agt(wsb+bRV+e);
    __syncthreads();
    int ks2 = tid>>4, cc = tid&15;
    int yc = (ci<<4) + cc;
    float a = 0.f;
    const float* wp = Wr + (size_t)(ks2*16)*256 + yc;
    const float* rp = srv + ks2*16;
    #pragma unroll
    for (int k=0;k<16;++k) a = fmaf(rp[k], wp[(size_t)k*256], a);
    ysum[ks2*16 + cc] = a;
    __syncthreads();
    if (tid < 16){
      float sm = 0.f;
      #pragma unroll
      for (int p=0;p<16;++p) sm += ysum[p*16 + tid];
      int yc2 = (ci<<4) + tid;
      out[((size_t)(b*256 + 255))*256 + yc2] = ld_agt(wsb+bYH+yc2) + sm;
    }
  }
}

extern "C" void kernel_launch(void* const* d_in, const int* in_sizes, int n_in,
                              void* d_out, int out_size, void* d_ws, size_t ws_size,
                              hipStream_t stream) {
  (void)in_sizes; (void)out_size;
  if (n_in < 9) return;
  const float* xin = (const float*)d_in[0];
  const float* Wx  = (const float*)d_in[1];
  const float* Wh  = (const float*)d_in[2];
  const float* bl  = (const float*)d_in[3];
  const float* Wxi = (const float*)d_in[4];
  const float* bxi = (const float*)d_in[5];
  const float* Wy  = (const float*)d_in[6];
  const float* Wr  = (const float*)d_in[7];
  const float* by  = (const float*)d_in[8];
  float* out = (float*)d_out;
  float* ws  = (float*)d_ws;
  if (ws_size < WS_TOTAL*sizeof(float)) return;

  hipLaunchKernelGGL(k_zero, dim3(512), dim3(256), 0, stream, ws);
  hipLaunchKernelGGL(k_dnc, dim3(NB), dim3(NT), 0, stream,
                     xin, Wx, Wh, bl, Wxi, bxi, Wy, Wr, by, out, ws);
}

// Round 17
// 23315.163 us; speedup vs baseline: 1.2865x; 1.0021x over previous
//
#include <hip/hip_runtime.h>
#include <cstddef>

#define DEV __device__ __forceinline__

// ---- dims: B=16 S=256 IN_DIM=264 H=512 4H=2048 XI=471 N=256 M=64 R=4 OUT=256
constexpr int S_ = 256;
constexpr int NB = 256;
constexpr int NT = 256;

// R16 post-mortem: all byte/protocol/clock/poll theories falsified; surviving
// model = serial cross-block round-trips (~3-4us each under load) x ~25/step.
// R17: merge C into D (5->4 phases). Every block redundantly computes ctrl
// (usage/sort/alloc) + write-content softmax from xi; usage/prec/w_w(t-1)
// become per-thread REGISTERS (updated identically in all 16 crew blocks).
// mem/NRM double-buffered by parity (content reads bank t&1, owners write
// bank (t+1)&1; E reads (t+1)&1). BWDP parity-buffered, zeroed in B.
// E self-computes knl + pi from xi. ws 7.2MB (R15 proved >=10.2MB OK).

// per-batch region offsets (floats), stride PB, base ws + b*PB
constexpr size_t bH    = 0;       // 2x512 h ping-pong [agent]
constexpr size_t bC    = 1024;    // 512 LSTM c [private: block ci]
constexpr size_t bXI   = 1536;    // 512 (471 used) [agent]
constexpr size_t bRV   = 2048;    // 256 [agent]
constexpr size_t bYH   = 2304;    // 256 [agent]
constexpr size_t bWR   = 2560;    // 4x256 [agent]
constexpr size_t bFWD  = 3584;    // 4x256 [agent]
constexpr size_t bBWDP = 4608;    // 2 parity x 4 slots x 1024 [agent zero + dev atomicAdd]
constexpr size_t bFLG  = 12800;   // 16 crew flags x 32
constexpr size_t bMEM  = 13312;   // 2 parity x 256x64 [agent]
constexpr size_t bNRM  = 46080;   // 2 parity x 256 [agent]
constexpr size_t bLNK  = 46592;   // 256x256 [private: block ci owns rows 16ci..]
constexpr size_t PB    = 112128;
constexpr size_t WS_TOTAL = PB*16;   // ~7.18 MB (< proven 10.2 MB)

typedef unsigned long long u64_;
union F2U { u64_ u; float2 f; };
DEV float2 ld2_agt(const float* p){ F2U c; c.u=__hip_atomic_load((const u64_*)p,__ATOMIC_RELAXED,__HIP_MEMORY_SCOPE_AGENT); return c.f; }
DEV void   st2_agt(float* p, float2 v){ F2U c; c.f=v; __hip_atomic_store((u64_*)p,c.u,__ATOMIC_RELAXED,__HIP_MEMORY_SCOPE_AGENT); }
DEV float  ld_agt(const float* p){ return __hip_atomic_load((float*)p,__ATOMIC_RELAXED,__HIP_MEMORY_SCOPE_AGENT); }
DEV void   st_agt(float* p,float v){ __hip_atomic_store(p,v,__ATOMIC_RELAXED,__HIP_MEMORY_SCOPE_AGENT); }

DEV float sigm(float x){ return 1.0f/(1.0f+expf(-x)); }
DEV float oneplus_(float x){ float sp = (x>20.0f)? x : log1pf(expf(x)); return 1.0f+sp; }

DEV float wredsum(float v){
  #pragma unroll
  for (int o=32;o>0;o>>=1) v += __shfl_xor(v,o);
  return v;
}
DEV float hredsum32(float v){
  #pragma unroll
  for (int o=16;o>0;o>>=1) v += __shfl_xor(v,o);
  return v;
}
DEV float wredmax(float v){
  #pragma unroll
  for (int o=32;o>0;o>>=1) v = fmaxf(v,__shfl_xor(v,o));
  return v;
}
DEV float bredsum(float v, float* red){
  v = wredsum(v);
  if ((threadIdx.x&63)==0) red[threadIdx.x>>6]=v;
  __syncthreads();
  float r = red[0]+red[1]+red[2]+red[3];
  __syncthreads();
  return r;
}
DEV float bredmax(float v, float* red){
  v = wredmax(v);
  if ((threadIdx.x&63)==0) red[threadIdx.x>>6]=v;
  __syncthreads();
  float r = fmaxf(fmaxf(red[0],red[1]),fmaxf(red[2],red[3]));
  __syncthreads();
  return r;
}

// crew barrier, single-round busy spin (R14-proven)
DEV void cbar(float* wsb, unsigned ep, int ci){
  unsigned* flg = (unsigned*)(wsb + bFLG);
  __syncthreads();
  if (threadIdx.x < 64){
    if (threadIdx.x == 0)
      __hip_atomic_store(flg + (size_t)ci*32, ep, __ATOMIC_RELAXED, __HIP_MEMORY_SCOPE_AGENT);
    const int l = threadIdx.x;
    bool ok;
    do {
      unsigned v = (l<16) ? __hip_atomic_load(flg + (size_t)l*32,
                      __ATOMIC_RELAXED, __HIP_MEMORY_SCOPE_AGENT) : ep;
      ok = __all(v >= ep);
    } while (!ok);
  }
  __syncthreads();
}

__global__ void k_zero(float* __restrict__ ws){
  size_t i = (size_t)blockIdx.x*blockDim.x + threadIdx.x;
  size_t st = (size_t)gridDim.x*blockDim.x;
  for (; i<WS_TOTAL; i+=st) ws[i]=0.0f;
}

__global__ __launch_bounds__(NT, 2) void k_dnc(
    const float* __restrict__ xin, const float* __restrict__ Wx,
    const float* __restrict__ Wh,  const float* __restrict__ bl,
    const float* __restrict__ Wxi, const float* __restrict__ bxi,
    const float* __restrict__ Wy,  const float* __restrict__ Wr,
    const float* __restrict__ by,  float* __restrict__ out,
    float* __restrict__ ws)
{
  __shared__ float smem[14336];   // 57 KB
  const int tid  = threadIdx.x;
  const int bid  = blockIdx.x;
  const int lane = tid & 63, wv = tid >> 6;
  const int half = lane >> 5, l32 = lane & 31;
  // crew mapping: XCD x = bid%8; q = bid/8; s = q&1; ci = q>>1; batch = x+8s
  const int x  = bid & 7;
  const int q  = bid >> 3;
  const int s  = q & 1;
  const int ci = q >> 1;
  const int b  = x + (s<<3);
  float* wsb = ws + (size_t)b*PB;
  unsigned ep = 0;
  // register-carried per-thread ctrl state (identical in all crew blocks)
  float usg = 0.f;   // usage[n]
  float prc = 0.f;   // precedence[n]
  float wwp = 0.f;   // w_w(t-1)[n]

  for (int t=0; t<S_; ++t){
    // ================= A: gates GEMM (pipelined) + LSTM + y(t-1) =================
    {
      float* sact = smem;          // 1032 (pad 1040)
      float* sred = smem + 1040;   // 8x128
      float* gall = smem + 2064;   // 128
      float* ysum = smem + 2192;   // 256
      const float* hrd = wsb + bH + (size_t)(t&1)*512;
      float* hwr = wsb + bH + (size_t)((t+1)&1)*512;
      for (int e=tid; e<1032; e+=NT){
        float v;
        if (e < 264)      v = xin[((size_t)(b*256+t))*264 + e];
        else if (e < 520) v = ld_agt(wsb + bRV + (e-264));
        else              v = ld_agt(hrd + (e-520));
        sact[e] = v;
      }
      __syncthreads();
      if (t > 0){
        int ks2 = tid>>4, cc = tid&15;
        int yc = (ci<<4) + cc;
        float a = 0.f;
        const float* wp = Wr + (size_t)(ks2*16)*256 + yc;
        const float* rp = sact + 264 + ks2*16;
        #pragma unroll
        for (int k=0;k<16;++k) a = fmaf(rp[k], wp[(size_t)k*256], a);
        ysum[ks2*16 + cc] = a;
        __syncthreads();
        if (tid < 16){
          float sm = 0.f;
          #pragma unroll
          for (int p=0;p<16;++p) sm += ysum[p*16 + tid];
          int yc2 = (ci<<4) + tid;
          out[((size_t)(b*256 + (t-1)))*256 + yc2] = ld_agt(wsb+bYH+yc2) + sm;
        }
        __syncthreads();
      }
      {
        const int colq = tid & 31;
        const int ksA  = tid >> 5;
        const int g    = colq >> 3;
        const int col  = (g<<9) + (ci<<5) + ((colq&7)<<2);
        float4 acc; acc.x=0.f; acc.y=0.f; acc.z=0.f; acc.w=0.f;
        const float4* wp; const float* xp; int kn;
        if (ksA < 4){
          int k0 = ksA*130; kn = 130;
          wp = (const float4*)(Wx + (size_t)k0*2048 + col);
          xp = sact + k0;
        } else {
          int k0 = (ksA-4)*128; kn = 128;
          wp = (const float4*)(Wh + (size_t)k0*2048 + col);
          xp = sact + 520 + k0;
        }
        const int nch = (kn+7)>>3;
        float4 buf[8];
        #pragma unroll
        for (int i=0;i<8;++i){
          int kk = (i<kn)? i : kn-1;
          buf[i] = wp[(size_t)kk*512];
        }
        for (int c=0; c<nch; ++c){
          float4 nbuf[8];
          int nb0 = (c+1)<<3;
          #pragma unroll
          for (int i=0;i<8;++i){
            int kk = nb0+i; kk = (kk<kn)? kk : kn-1;
            nbuf[i] = wp[(size_t)kk*512];
          }
          int kb = c<<3;
          #pragma unroll
          for (int i=0;i<8;++i){
            float xv = (kb+i<kn)? xp[kb+i] : 0.f;
            acc.x=fmaf(buf[i].x,xv,acc.x); acc.y=fmaf(buf[i].y,xv,acc.y);
            acc.z=fmaf(buf[i].z,xv,acc.z); acc.w=fmaf(buf[i].w,xv,acc.w);
          }
          #pragma unroll
          for (int i=0;i<8;++i) buf[i]=nbuf[i];
        }
        *(float4*)(sred + ksA*128 + (colq<<2)) = acc;
      }
      __syncthreads();
      if (tid < 128){
        int gg = tid>>5, cc = (ci<<5) + (tid&31);
        float sm = bl[(gg<<9)+cc];
        #pragma unroll
        for (int p=0;p<8;++p) sm += sred[(p<<7) + tid];
        gall[tid] = sm;
      }
      __syncthreads();
      if (tid < 32){
        int j = (ci<<5) + tid;
        float gi=gall[tid], gf=gall[32+tid], gg2=gall[64+tid], go=gall[96+tid];
        float co = wsb[bC + j];
        float cn = sigm(gf)*co + sigm(gi)*tanhf(gg2);
        float hn = sigm(go)*tanhf(cn);
        wsb[bC + j] = cn;
        st_agt(hwr + j, hn);
      }
    }
    ep++; cbar(wsb, ep, ci);

    // ================= B: xi / YH + zero BWDP parity(t) =================
    {
      float* shh = smem;         // 512
      float* sp  = smem + 512;   // 8x30
      float* syh = smem + 768;   // 16x16
      const float* hcur = wsb + bH + (size_t)((t+1)&1)*512;
      for (int e=tid; e<512; e+=NT) shh[e] = ld_agt(hcur + e);
      __syncthreads();
      const int nc = (ci<15) ? 30 : 21;
      if (tid < 240){
        int ks = tid/30, cc = tid%30;
        if (cc < nc){
          int col = ci*30 + cc;
          float a = 0.f;
          const float* wp = Wxi + (size_t)(ks*64)*471 + col;
          const float* hp = shh + ks*64;
          #pragma unroll 8
          for (int k=0;k<64;++k) a = fmaf(hp[k], wp[(size_t)k*471], a);
          sp[ks*30 + cc] = a;
        }
      }
      {
        int ks = tid>>4, cc = tid&15;
        int col = (ci<<4) + cc;
        float a = 0.f;
        const float* wp = Wy + (size_t)(ks*32)*256 + col;
        const float* hp = shh + ks*32;
        #pragma unroll 8
        for (int k=0;k<32;++k) a = fmaf(hp[k], wp[(size_t)k*256], a);
        syh[ks*16 + cc] = a;
      }
      // zero this block's slice of BWDP parity(t) (last read in E(t-2))
      {
        float2 z; z.x=0.f; z.y=0.f;
        float* bz = wsb + bBWDP + (size_t)(t&1)*4096 + (size_t)ci*256;
        if (tid < 128) st2_agt(bz + (tid<<1), z);
      }
      __syncthreads();
      if (tid < nc){
        float sm = bxi[ci*30 + tid];
        #pragma unroll
        for (int p=0;p<8;++p) sm += sp[p*30 + tid];
        st_agt(wsb + bXI + ci*30 + tid, sm);
      }
      if (tid < 16){
        float sm = by[(ci<<4) + tid];
        #pragma unroll
        for (int p=0;p<16;++p) sm += syh[p*16 + tid];
        st_agt(wsb + bYH + (ci<<4) + tid, sm);
      }
    }
    ep++; cbar(wsb, ep, ci);

    // ======== D': redundant ctrl + content + link + mem (merged C+D) ========
    {
      float* xv    = smem;          // 512
      float* uu    = smem + 512;    // 256
      float* sa    = smem + 768;    // 256
      float* sb    = smem + 1024;   // 256
      float* red   = smem + 1280;   // 8
      float* knw   = smem + 1344;   // 64
      float* sims  = smem + 1408;   // 256
      float* wwl   = smem + 1664;   // 256
      float* wrl   = smem + 1920;   // 4x16
      float* fpart = smem + 1984;   // 256
      const int ri = ci<<4;
      if (tid < 240){
        float2 v = ld2_agt(wsb + bXI + (tid<<1));
        xv[tid<<1]=v.x; xv[(tid<<1)+1]=v.y;
      }
      __syncthreads();
      const int n = tid;
      const float* wrb = wsb + bWR;
      float wr0=ld_agt(wrb+n), wr1=ld_agt(wrb+256+n),
            wr2=ld_agt(wrb+512+n), wr3=ld_agt(wrb+768+n);
      if (tid < 64) wrl[(tid>>4)*16 + (tid&15)] = ld_agt(wrb + ((size_t)(tid>>4)<<8) + ri + (tid&15));
      // --- ctrl (redundant; usage/prec/w_w carried in registers) ---
      float f0=sigm(xv[453]), f1=sigm(xv[454]), f2v=sigm(xv[455]), f3=sigm(xv[456]);
      float psi=(1.f-f0*wr0)*(1.f-f1*wr1)*(1.f-f2v*wr2)*(1.f-f3*wr3);
      float un=(usg + wwp - usg*wwp)*psi;
      usg = un;
      uu[n]=un;
      __syncthreads();
      int rk=0;
      #pragma unroll 8
      for (int j=0;j<256;++j){
        float uj=uu[j];
        rk += (uj<un)||(uj==un && j<n);
      }
      sa[rk]=un;
      __syncthreads();
      float* cur=sa; float* nxt=sb;
      for (int off=1;off<256;off<<=1){
        float v=cur[n]; if (n>=off) v*=cur[n-off];
        nxt[n]=v;
        __syncthreads();
        float* tmp=cur; cur=nxt; nxt=tmp;
      }
      float pe = rk ? cur[rk-1] : 1.f;
      float al = (1.f-un)*pe;
      float sumA = bredsum(al, red);
      float ga = sigm(xv[457]), gw = sigm(xv[458]);
      // --- write-content softmax (reads mem bank t&1: state after t-1) ---
      if (wv==0){
        float kv=xv[260+lane];
        float s2=wredsum(kv*kv);
        float bw_=oneplus_(xv[324]);
        knw[lane]=kv*bw_/(sqrtf(s2)+1e-6f);
      }
      __syncthreads();
      const float* memR = wsb + bMEM + (size_t)(t&1)*16384;
      const float* nrmR = wsb + bNRM + (size_t)(t&1)*256;
      for (int i2=0;i2<32;++i2){
        int n2=(wv<<6)+(i2<<1)+half;
        float2 v=ld2_agt(memR+(n2<<6)+(l32<<1));
        float d=hredsum32(v.x*knw[l32<<1]+v.y*knw[(l32<<1)+1]);
        if (l32==0) sims[n2]=d/(sqrtf(ld_agt(nrmR+n2))+1e-6f);
      }
      __syncthreads();
      float sv=sims[tid];
      float mx=bredmax(sv,red); float e=expf(sv-mx); float sm=bredsum(e,red);
      float cw = e/sm;
      // --- w_w, prec (register), link slice, fwd/bwd, mem update ---
      float wj = gw*(ga*al + (1.f-ga)*cw);
      wwl[n] = wj;
      float sww = gw*(ga*sumA + (1.f-ga));
      float pj = prc;                    // prec(t-1)
      prc = (1.f-sww)*prc + wj;          // prec(t)
      wwp = wj;                          // w_w(t) for next usage update
      __syncthreads();
      float b0=0.f,b1=0.f,b2=0.f,b3=0.f;
      float* lrow = wsb + bLNK + (size_t)ri*256;
      for (int il=0; il<16; ++il){
        int irow = ri + il;
        float Lo = lrow[il*256 + n];
        float wi = wwl[irow];
        float Ln = (1.f - wi - wj)*Lo + wi*pj;
        if (irow == n) Ln = 0.f;
        lrow[il*256 + n] = Ln;
        float s0=wredsum(Ln*wr0), s1=wredsum(Ln*wr1), s2=wredsum(Ln*wr2), s3=wredsum(Ln*wr3);
        if (lane==0){
          fpart[wv*64 + il]      = s0;
          fpart[wv*64 + 16 + il] = s1;
          fpart[wv*64 + 32 + il] = s2;
          fpart[wv*64 + 48 + il] = s3;
        }
        b0=fmaf(Ln, wrl[il],    b0);
        b1=fmaf(Ln, wrl[16+il], b1);
        b2=fmaf(Ln, wrl[32+il], b2);
        b3=fmaf(Ln, wrl[48+il], b3);
      }
      __syncthreads();
      if (tid < 64){
        int r = tid>>4, il = tid&15;
        float smf = fpart[r*16+il] + fpart[64+r*16+il] + fpart[128+r*16+il] + fpart[192+r*16+il];
        st_agt(wsb+bFWD + ((size_t)r<<8) + ri + il, smf);
      }
      float* slot = wsb + bBWDP + (size_t)(t&1)*4096 + (size_t)(ci&3)*1024;
      atomicAdd(&slot[n], b0);      atomicAdd(&slot[256+n], b1);
      atomicAdd(&slot[512+n], b2);  atomicAdd(&slot[768+n], b3);
      // mem update rows ri..ri+15: read bank t&1, write bank (t+1)&1
      {
        float* memW = wsb + bMEM + (size_t)((t+1)&1)*16384;
        float* nrmW = wsb + bNRM + (size_t)((t+1)&1)*256;
        int row2 = tid>>5, c2 = tid&31;
        float2 er, wv2;
        er.x = sigm(xv[325+(c2<<1)]);  er.y = sigm(xv[326+(c2<<1)]);
        wv2.x = xv[389+(c2<<1)];       wv2.y = xv[390+(c2<<1)];
        #pragma unroll
        for (int it=0; it<2; ++it){
          int row = ri + row2 + it*8;
          float wwn = wwl[row];
          float2 v = ld2_agt(memR + ((size_t)row<<6) + (c2<<1));
          v.x = v.x*(1.f - wwn*er.x) + wwn*wv2.x;
          v.y = v.y*(1.f - wwn*er.y) + wwn*wv2.y;
          st2_agt(memW + ((size_t)row<<6) + (c2<<1), v);
          float s2 = hredsum32(v.x*v.x + v.y*v.y);
          if (c2==0) st_agt(nrmW+row, s2);
        }
      }
    }
    ep++; cbar(wsb, ep, ci);

    // ================= E: read heads (ci<4; knl & pi self-computed) =================
    if (ci < 4){
      int r = ci;
      float* knl=smem; float* sims=smem+64; float* wrs=smem+320;
      float* part=smem+576; float* red=smem+832;
      if (wv==0){
        float kv=ld_agt(wsb+bXI+(r<<6)+lane);
        float s2=wredsum(kv*kv);
        float br=oneplus_(ld_agt(wsb+bXI+256+r));
        knl[lane]=kv*br/(sqrtf(s2)+1e-6f);
      }
      __syncthreads();
      const float* memb = wsb + bMEM + (size_t)((t+1)&1)*16384;  // mem(t)
      const float* nrmb = wsb + bNRM + (size_t)((t+1)&1)*256;
      {
        int row2 = tid>>5, c2 = tid&31;
        for (int it=0; it<32; ++it){
          int n2 = row2 + it*8;
          float2 v = ld2_agt(memb + ((size_t)n2<<6) + (c2<<1));
          float d = hredsum32(v.x*knl[c2<<1] + v.y*knl[(c2<<1)+1]);
          if (c2==0) sims[n2] = d/(sqrtf(ld_agt(nrmb+n2))+1e-6f);
        }
      }
      __syncthreads();
      float sv=sims[tid];
      float mx=bredmax(sv,red); float e=expf(sv-mx); float sm=bredsum(e,red);
      float cr=e/sm;
      float q0=ld_agt(wsb+bXI+459+r*3), q1=ld_agt(wsb+bXI+460+r*3), q2=ld_agt(wsb+bXI+461+r*3);
      float qm=fmaxf(q0,fmaxf(q1,q2));
      float e0=expf(q0-qm), e1=expf(q1-qm), e2=expf(q2-qm);
      float qs=e0+e1+e2;
      float p0=e0/qs, p1=e1/qs, p2=e2/qs;
      const float* bwdp = wsb + bBWDP + (size_t)(t&1)*4096;
      float bwv = ld_agt(bwdp + ((size_t)r<<8) + tid)
                + ld_agt(bwdp + 1024 + ((size_t)r<<8) + tid)
                + ld_agt(bwdp + 2048 + ((size_t)r<<8) + tid)
                + ld_agt(bwdp + 3072 + ((size_t)r<<8) + tid);
      float wr = p0*bwv + p1*cr + p2*ld_agt(wsb+bFWD+((size_t)r<<8)+tid);
      st_agt(wsb+bWR+((size_t)r<<8)+tid, wr);
      wrs[tid]=wr;
      __syncthreads();
      {
        int m = tid&63, ksn = tid>>6;
        float a=0.f;
        #pragma unroll 8
        for (int n0=0;n0<64;++n0){
          int n2 = (ksn<<6)+n0;
          a = fmaf(wrs[n2], ld_agt(memb + ((size_t)n2<<6) + m), a);
        }
        part[(ksn<<6)+m]=a;
      }
      __syncthreads();
      if (tid<64)
        st_agt(wsb+bRV+(r<<6)+tid, part[tid]+part[64+tid]+part[128+tid]+part[192+tid]);
    }
    ep++; cbar(wsb, ep, ci);
  }

  // ---- epilogue: y(255) = YH + rv(255) @ Wr ----
  {
    float* srv  = smem;
    float* ysum = smem + 256;
    for (int e=tid;e<256;e+=NT) srv[e]=ld_agt(wsb+bRV+e);
    __syncthreads();
    int ks2 = tid>>4, cc = tid&15;
    int yc = (ci<<4) + cc;
    float a = 0.f;
    const float* wp = Wr + (size_t)(ks2*16)*256 + yc;
    const float* rp = srv + ks2*16;
    #pragma unroll
    for (int k=0;k<16;++k) a = fmaf(rp[k], wp[(size_t)k*256], a);
    ysum[ks2*16 + cc] = a;
    __syncthreads();
    if (tid < 16){
      float sm = 0.f;
      #pragma unroll
      for (int p=0;p<16;++p) sm += ysum[p*16 + tid];
      int yc2 = (ci<<4) + tid;
      out[((size_t)(b*256 + 255))*256 + yc2] = ld_agt(wsb+bYH+yc2) + sm;
    }
  }
}

extern "C" void kernel_launch(void* const* d_in, const int* in_sizes, int n_in,
                              void* d_out, int out_size, void* d_ws, size_t ws_size,
                              hipStream_t stream) {
  (void)in_sizes; (void)out_size;
  if (n_in < 9) return;
  const float* xin = (const float*)d_in[0];
  const float* Wx  = (const float*)d_in[1];
  const float* Wh  = (const float*)d_in[2];
  const float* bl  = (const float*)d_in[3];
  const float* Wxi = (const float*)d_in[4];
  const float* bxi = (const float*)d_in[5];
  const float* Wy  = (const float*)d_in[6];
  const float* Wr  = (const float*)d_in[7];
  const float* by  = (const float*)d_in[8];
  float* out = (float*)d_out;
  float* ws  = (float*)d_ws;
  if (ws_size < WS_TOTAL*sizeof(float)) return;

  hipLaunchKernelGGL(k_zero, dim3(512), dim3(256), 0, stream, ws);
  hipLaunchKernelGGL(k_dnc, dim3(NB), dim3(NT), 0, stream,
                     xin, Wx, Wh, bl, Wxi, bxi, Wy, Wr, by, out, ws);
}

// Round 18
// 21919.629 us; speedup vs baseline: 1.3684x; 1.0637x over previous
//
#include <hip/hip_runtime.h>
#include <cstddef>

#define DEV __device__ __forceinline__

// ---- dims: B=16 S=256 IN_DIM=264 H=512 4H=2048 XI=471 N=256 M=64 R=4 OUT=256
constexpr int S_ = 256;
constexpr int NB = 256;
constexpr int NT = 256;

// R17 post-mortem: hop-count model falsified; surviving model = phase-A weight
// re-stream at ~580GB/s effective (dur ~= FETCH/580 across R10/13/14/16/17).
// R18 = R13 with the residency bug FIXED: block (x,s,ci) owns h-indices
// [jb*32, jb*32+32), jb=x+8s, so its 4 gate-col runs (Q*512+jb*32+u) are
// 128B-aligned 32-col runs. XCD x's slice = 1.06MB -> L2-resident all steps;
// coalescing improves 8->32 consecutive cols. Everything else = R13 verbatim.

// per-batch region offsets (floats), stride PB, base ws + b*PB
constexpr size_t bH    = 0;       // 2x512 h ping-pong [sys; written by gates blocks]
constexpr size_t bC    = 1024;    // 512 LSTM c [private: gates block (x,s)]
constexpr size_t bXI   = 1536;    // 512 (471 used) [agent]
constexpr size_t bKNR  = 2048;    // 256 [agent]
constexpr size_t bALC  = 2304;    // 256 [agent]
constexpr size_t bCW   = 2560;    // 256 [agent]
constexpr size_t bWW   = 2816;    // 256 [agent]
constexpr size_t bNRM  = 3072;    // 256 [agent]
constexpr size_t bUSG  = 3328;    // 256 [private: ctrl block]
constexpr size_t bRV   = 3584;    // 256 [sys]
constexpr size_t bYH   = 3840;    // 256 [agent]
constexpr size_t bSCL  = 4096;    // 32  [agent]
constexpr size_t bPI   = 4128;    // 32  [agent]
constexpr size_t bERS  = 4160;    // 64  [agent]
constexpr size_t bWVC  = 4224;    // 64  [agent]
constexpr size_t bPRC  = 4288;    // 2x256 [agent]
constexpr size_t bWR   = 4800;    // 4x256 [agent]
constexpr size_t bFWD  = 5824;    // 4x256 [agent]
constexpr size_t bBWDP = 6848;    // 4 slots x 4 heads x 256 [agent zero + dev atomicAdd + agent read]
constexpr size_t bFLG  = 10944;   // 16 crew flags x 32 (1/128B line)
constexpr size_t bMEM  = 11456;   // 256x64 [agent]
constexpr size_t bLNK  = 27840;   // 256x256 [private: crew block ci owns rows 16ci..]
constexpr size_t bHCT  = 93376;   // h arrival counter [dev atomicAdd + sys poll]
constexpr size_t bSTF  = 93408;   // state flag (rv of step t done) [sys]
constexpr size_t PB    = 93440;
constexpr size_t WS_TOTAL = PB*16;   // ~5.98 MB

typedef unsigned long long u64_;
union F2U { u64_ u; float2 f; };
DEV float2 ld2_agt(const float* p){ F2U c; c.u=__hip_atomic_load((const u64_*)p,__ATOMIC_RELAXED,__HIP_MEMORY_SCOPE_AGENT); return c.f; }
DEV void   st2_agt(float* p, float2 v){ F2U c; c.f=v; __hip_atomic_store((u64_*)p,c.u,__ATOMIC_RELAXED,__HIP_MEMORY_SCOPE_AGENT); }
DEV float  ld_agt(const float* p){ return __hip_atomic_load((float*)p,__ATOMIC_RELAXED,__HIP_MEMORY_SCOPE_AGENT); }
DEV void   st_agt(float* p,float v){ __hip_atomic_store(p,v,__ATOMIC_RELAXED,__HIP_MEMORY_SCOPE_AGENT); }
DEV float  ld_sys(const float* p){ return __hip_atomic_load((float*)p,__ATOMIC_RELAXED,__HIP_MEMORY_SCOPE_SYSTEM); }
DEV void   st_sys(float* p,float v){ __hip_atomic_store(p,v,__ATOMIC_RELAXED,__HIP_MEMORY_SCOPE_SYSTEM); }

DEV float sigm(float x){ return 1.0f/(1.0f+expf(-x)); }
DEV float oneplus_(float x){ float sp = (x>20.0f)? x : log1pf(expf(x)); return 1.0f+sp; }

DEV float wredsum(float v){
  #pragma unroll
  for (int o=32;o>0;o>>=1) v += __shfl_xor(v,o);
  return v;
}
DEV float hredsum32(float v){
  #pragma unroll
  for (int o=16;o>0;o>>=1) v += __shfl_xor(v,o);
  return v;
}
DEV float wredmax(float v){
  #pragma unroll
  for (int o=32;o>0;o>>=1) v = fmaxf(v,__shfl_xor(v,o));
  return v;
}
DEV float bredsum(float v, float* red){
  v = wredsum(v);
  if ((threadIdx.x&63)==0) red[threadIdx.x>>6]=v;
  __syncthreads();
  float r = red[0]+red[1]+red[2]+red[3];
  __syncthreads();
  return r;
}
DEV float bredmax(float v, float* red){
  v = wredmax(v);
  if ((threadIdx.x&63)==0) red[threadIdx.x>>6]=v;
  __syncthreads();
  float r = fmaxf(fmaxf(red[0],red[1]),fmaxf(red[2],red[3]));
  __syncthreads();
  return r;
}

// crew barrier, single-round (R10-proven): post own flag, all poll all 16.
DEV void cbar(float* wsb, unsigned ep, int ci){
  unsigned* flg = (unsigned*)(wsb + bFLG);
  __syncthreads();
  if (threadIdx.x < 64){
    if (threadIdx.x == 0)
      __hip_atomic_store(flg + (size_t)ci*32, ep, __ATOMIC_RELAXED, __HIP_MEMORY_SCOPE_AGENT);
    const int l = threadIdx.x;
    bool ok;
    do {
      unsigned v = (l<16) ? __hip_atomic_load(flg + (size_t)l*32,
                      __ATOMIC_RELAXED, __HIP_MEMORY_SCOPE_AGENT) : ep;
      ok = __all(v >= ep);
      if (!ok) __builtin_amdgcn_s_sleep(1);
    } while (!ok);
  }
  __syncthreads();
}

__global__ void k_zero(float* __restrict__ ws){
  size_t i = (size_t)blockIdx.x*blockDim.x + threadIdx.x;
  size_t st = (size_t)gridDim.x*blockDim.x;
  for (; i<WS_TOTAL; i+=st) ws[i]=0.0f;
}

__global__ __launch_bounds__(NT, 2) void k_dnc(
    const float* __restrict__ xin, const float* __restrict__ Wx,
    const float* __restrict__ Wh,  const float* __restrict__ bl,
    const float* __restrict__ Wxi, const float* __restrict__ bxi,
    const float* __restrict__ Wy,  const float* __restrict__ Wr,
    const float* __restrict__ by,  float* __restrict__ out,
    float* __restrict__ ws)
{
  __shared__ float smem[14336];   // 57 KB
  const int tid  = threadIdx.x;
  const int bid  = blockIdx.x;
  const int lane = tid & 63, wv = tid >> 6;
  // crew mapping (R9..R17-proven): XCD x = bid%8; q=bid/8; s=q&1; ci=q>>1; b=x+8s
  const int x  = bid & 7;
  const int q  = bid >> 3;
  const int s  = q & 1;
  const int ci = q >> 1;
  const int b  = x + (s<<3);
  float* wsb = ws + (size_t)b*PB;
  // gates role: block (x,s,ci) computes, for batch gb=ci, the h-indices
  // j in [jb*32, jb*32+32), jb = x+8s, via cols {Q*512 + jb*32 + u}:
  // four 128B-aligned 32-col runs. XCD x holds jb in {x, x+8} -> 1.06MB
  // resident weight slice, fully coalesced 32-lane line reads.
  const int gb = ci;
  const int jb = x + (s<<3);
  float* wsg = ws + (size_t)gb*PB;
  unsigned ep = 0;

  for (int t=0; t<S_; ++t){
    // ================= G: distributed gates GEMM + fused LSTM =================
    {
      unsigned* stf = (unsigned*)(wsg + bSTF);
      if (tid==0){
        while (__hip_atomic_load(stf, __ATOMIC_RELAXED, __HIP_MEMORY_SCOPE_SYSTEM) < (unsigned)t)
          __builtin_amdgcn_s_sleep(1);
      }
      __syncthreads();
      float* sact = smem;          // 1032 (pad 1040)
      float* sred = smem + 1040;   // 256
      float* g4   = smem + 1296;   // 128
      const float* hrd = wsg + bH + (size_t)(t&1)*512;
      for (int e=tid; e<1032; e+=NT){
        float v;
        if (e < 264)      v = xin[((size_t)(gb*256+t))*264 + e];
        else if (e < 520) v = ld_sys(wsg + bRV + (e-264));
        else              v = ld_sys(hrd + (e-520));
        sact[e] = v;
      }
      __syncthreads();
      // 2-way ksplit x 128 cols, unroll-16 prefetch (L2-resident slice)
      {
        const int ks2 = tid>>7, cc = tid&127;
        const int Q = cc>>5, u = cc&31;
        const int col = (Q<<9) + (jb<<5) + u;
        const float* W; const float* xp; int kn;
        if (ks2==0){ W = Wx + col; xp = sact;       kn = 520; }
        else       { W = Wh + col; xp = sact + 520; kn = 512; }
        float acc = 0.f;
        float buf[16];
        const int nch = (kn+15)>>4;
        #pragma unroll
        for (int i=0;i<16;++i){
          int kk = (i<kn)? i : kn-1;
          buf[i] = W[(size_t)kk*2048];
        }
        for (int c2=0; c2<nch; ++c2){
          float nb[16];
          int nb0 = (c2+1)<<4;
          #pragma unroll
          for (int i=0;i<16;++i){
            int kk = nb0+i; kk = (kk<kn)? kk : kn-1;
            nb[i] = W[(size_t)kk*2048];
          }
          int kb = c2<<4;
          #pragma unroll
          for (int i=0;i<16;++i){
            float xv = (kb+i<kn)? xp[kb+i] : 0.f;
            acc = fmaf(buf[i], xv, acc);
          }
          #pragma unroll
          for (int i=0;i<16;++i) buf[i]=nb[i];
        }
        sred[tid] = acc;
      }
      __syncthreads();
      if (tid < 128){
        const int Q = tid>>5, u = tid&31;
        const int col = (Q<<9) + (jb<<5) + u;
        g4[tid] = sred[tid] + sred[128+tid] + bl[col];
      }
      __syncthreads();
      if (tid < 32){
        int j = (jb<<5) + tid;
        float gi=g4[tid], gf=g4[32+tid], gg2=g4[64+tid], go=g4[96+tid];
        float co = wsg[bC + j];          // private to this gates block
        float cn = sigm(gf)*co + sigm(gi)*tanhf(gg2);
        float hn = sigm(go)*tanhf(cn);
        wsg[bC + j] = cn;
        st_sys(wsg + bH + (size_t)((t+1)&1)*512 + j, hn);
      }
      __syncthreads();   // drain h stores (vmcnt 0) before arrival
      if (tid==0) atomicAdd((unsigned*)(wsg + bHCT), 1u);
    }

    // ================= B: y(t-1) (no wait) ; then xi/YH after h arrives =================
    {
      float* srv  = smem;        // 256
      float* ysum = smem + 256;  // 256
      if (t > 0){
        for (int e=tid;e<256;e+=NT) srv[e]=ld_sys(wsb+bRV+e);
        __syncthreads();
        int ks2 = tid>>4, cc = tid&15;
        int yc = (ci<<4) + cc;
        float a = 0.f;
        const float* wp = Wr + (size_t)(ks2*16)*256 + yc;
        const float* rp = srv + ks2*16;
        #pragma unroll
        for (int k=0;k<16;++k) a = fmaf(rp[k], wp[(size_t)k*256], a);
        ysum[ks2*16 + cc] = a;
        __syncthreads();
        if (tid < 16){
          float sm = 0.f;
          #pragma unroll
          for (int p=0;p<16;++p) sm += ysum[p*16 + tid];
          int yc2 = (ci<<4) + tid;
          out[((size_t)(b*256 + (t-1)))*256 + yc2] = ld_agt(wsb+bYH+yc2) + sm;
        }
        __syncthreads();
      }
      unsigned* hct = (unsigned*)(wsb + bHCT);
      if (tid==0){
        while (__hip_atomic_load(hct, __ATOMIC_RELAXED, __HIP_MEMORY_SCOPE_SYSTEM) < 16u*(unsigned)(t+1))
          __builtin_amdgcn_s_sleep(1);
      }
      __syncthreads();
      float* shh = smem;         // 512
      float* sp  = smem + 512;   // 8x30
      float* syh = smem + 768;   // 16x16
      const float* hcur = wsb + bH + (size_t)((t+1)&1)*512;
      for (int e=tid; e<512; e+=NT) shh[e] = ld_sys(hcur + e);
      __syncthreads();
      const int nc = (ci<15) ? 30 : 21;
      if (tid < 240){
        int ks = tid/30, cc = tid%30;
        if (cc < nc){
          int col = ci*30 + cc;
          float a = 0.f;
          const float* wp = Wxi + (size_t)(ks*64)*471 + col;
          const float* hp = shh + ks*64;
          #pragma unroll 8
          for (int k=0;k<64;++k) a = fmaf(hp[k], wp[(size_t)k*471], a);
          sp[ks*30 + cc] = a;
        }
      }
      {
        int ks = tid>>4, cc = tid&15;
        int col = (ci<<4) + cc;
        float a = 0.f;
        const float* wp = Wy + (size_t)(ks*32)*256 + col;
        const float* hp = shh + ks*32;
        #pragma unroll 8
        for (int k=0;k<32;++k) a = fmaf(hp[k], wp[(size_t)k*256], a);
        syh[ks*16 + cc] = a;
      }
      __syncthreads();
      if (tid < nc){
        float sm = bxi[ci*30 + tid];
        #pragma unroll
        for (int p=0;p<8;++p) sm += sp[p*30 + tid];
        st_agt(wsb + bXI + ci*30 + tid, sm);
      }
      if (tid < 16){
        float sm = by[(ci<<4) + tid];
        #pragma unroll
        for (int p=0;p<16;++p) sm += syh[p*16 + tid];
        st_agt(wsb + bYH + (ci<<4) + tid, sm);
      }
    }
    ep++; cbar(wsb, ep, ci);

    // ================= C: ctrl(ci0) | content(ci1) | zero BWDP(ci2) =================
    if (ci == 0){
      float* xv = smem; float* uu = smem+512; float* sa = smem+768;
      float* sb = smem+1024; float* red = smem+1280;
      if (tid < 240){
        float2 v = ld2_agt(wsb + bXI + (tid<<1));
        xv[tid<<1]=v.x; xv[(tid<<1)+1]=v.y;
      }
      __syncthreads();
      int n = tid;
      float f0=sigm(xv[453]), f1=sigm(xv[454]), f2v=sigm(xv[455]), f3=sigm(xv[456]);
      const float* wrb = wsb + bWR;
      float psi=(1.f-f0*ld_agt(wrb+n))*(1.f-f1*ld_agt(wrb+256+n))
               *(1.f-f2v*ld_agt(wrb+512+n))*(1.f-f3*ld_agt(wrb+768+n));
      float uo=wsb[bUSG+n];
      float wwp=ld_agt(wsb+bWW+n);
      float un=(uo+wwp-uo*wwp)*psi;
      uu[n]=un; wsb[bUSG+n]=un;
      __syncthreads();
      int rk=0;
      #pragma unroll 8
      for (int j=0;j<256;++j){
        float uj=uu[j];
        rk += (uj<un)||(uj==un && j<n);
      }
      sa[rk]=un;
      __syncthreads();
      float* cur=sa; float* nxt=sb;
      for (int off=1;off<256;off<<=1){
        float v=cur[n]; if (n>=off) v*=cur[n-off];
        nxt[n]=v;
        __syncthreads();
        float* tmp=cur; cur=nxt; nxt=tmp;
      }
      float pe = rk ? cur[rk-1] : 1.f;
      float al = (1.f-un)*pe;
      st_agt(wsb+bALC+n, al);
      float sumA = bredsum(al, red);
      if (tid==0){
        st_agt(wsb+bSCL+0, sigm(xv[457]));
        st_agt(wsb+bSCL+1, sigm(xv[458]));
        st_agt(wsb+bSCL+2, sumA);
      }
      {
        int r=tid>>6, m=tid&63;
        float kv=xv[(r<<6)+m];
        float s2=wredsum(kv*kv);
        float br=oneplus_(xv[256+r]);
        st_agt(wsb+bKNR+tid, kv*br/(sqrtf(s2)+1e-6f));
      }
      if (tid<4){
        float p0=xv[459+tid*3], p1=xv[460+tid*3], p2=xv[461+tid*3];
        float mx=fmaxf(p0,fmaxf(p1,p2));
        float e0=expf(p0-mx), e1=expf(p1-mx), e2=expf(p2-mx);
        float sm=e0+e1+e2;
        st_agt(wsb+bPI+tid*3+0, e0/sm);
        st_agt(wsb+bPI+tid*3+1, e1/sm);
        st_agt(wsb+bPI+tid*3+2, e2/sm);
      }
      if (tid<64){
        st_agt(wsb+bERS+tid, sigm(xv[325+tid]));
        st_agt(wsb+bWVC+tid, xv[389+tid]);
      }
    } else if (ci == 1){
      float* knw=smem; float* sims=smem+64; float* red=smem+320;
      const int half = lane>>5, l32 = lane&31;
      if (wv==0){
        float kv=ld_agt(wsb+bXI+260+lane);
        float s2=wredsum(kv*kv);
        float bw_=oneplus_(ld_agt(wsb+bXI+324));
        knw[lane]=kv*bw_/(sqrtf(s2)+1e-6f);
      }
      __syncthreads();
      const float* memb=wsb+bMEM;
      for (int i2=0;i2<32;++i2){
        int n=(wv<<6)+(i2<<1)+half;
        float2 v=ld2_agt(memb+(n<<6)+(l32<<1));
        float d=hredsum32(v.x*knw[l32<<1]+v.y*knw[(l32<<1)+1]);
        if (l32==0) sims[n]=d/(sqrtf(ld_agt(wsb+bNRM+n))+1e-6f);
      }
      __syncthreads();
      float sv=sims[tid];
      float mx=bredmax(sv,red); float e=expf(sv-mx); float sm=bredsum(e,red);
      st_agt(wsb+bCW+tid, e/sm);
    } else if (ci == 2){
      for (int e=tid;e<4096;e+=NT) st_agt(wsb+bBWDP+e, 0.f);
    }
    ep++; cbar(wsb, ep, ci);

    // ================= D: link rows 16ci.. + fwd/bwd partials + mem/nrm/prec =================
    {
      float* wwl   = smem;         // 256
      float* wrl   = smem + 256;   // 4x16
      float* fpart = smem + 320;   // 4wv x 4r x 16
      float* sscl  = smem + 576;   // 4
      const int ri = ci<<4;
      if (tid < 3) sscl[tid] = ld_agt(wsb+bSCL+tid);
      __syncthreads();
      float ga = sscl[0], gw = sscl[1], sA = sscl[2];
      float sww = gw*(ga*sA + (1.f-ga));
      int j = tid;
      float wj = gw*(ga*ld_agt(wsb+bALC+j) + (1.f-ga)*ld_agt(wsb+bCW+j));
      wwl[j] = wj;
      if (ci == 1) st_agt(wsb+bWW+j, wj);
      float pj = ld_agt(wsb+bPRC + (size_t)(t&1)*256 + j);
      if (ci == 0) st_agt(wsb+bPRC + (size_t)((t+1)&1)*256 + j, (1.f-sww)*pj + wj);
      const float* wrb = wsb + bWR;
      float wr0=ld_agt(wrb+j), wr1=ld_agt(wrb+256+j),
            wr2=ld_agt(wrb+512+j), wr3=ld_agt(wrb+768+j);
      if (tid < 64) wrl[(tid>>4)*16 + (tid&15)] = ld_agt(wrb + ((size_t)(tid>>4)<<8) + ri + (tid&15));
      __syncthreads();
      float b0=0.f,b1=0.f,b2=0.f,b3=0.f;
      float* lrow = wsb + bLNK + (size_t)ri*256;   // private, L1/L2-resident
      for (int il=0; il<16; ++il){
        int irow = ri + il;
        float Lo = lrow[il*256 + j];
        float wi = wwl[irow];
        float Ln = (1.f - wi - wj)*Lo + wi*pj;
        if (irow == j) Ln = 0.f;
        lrow[il*256 + j] = Ln;
        float s0=wredsum(Ln*wr0), s1=wredsum(Ln*wr1), s2=wredsum(Ln*wr2), s3=wredsum(Ln*wr3);
        if (lane==0){
          fpart[wv*64 + il]      = s0;
          fpart[wv*64 + 16 + il] = s1;
          fpart[wv*64 + 32 + il] = s2;
          fpart[wv*64 + 48 + il] = s3;
        }
        b0=fmaf(Ln, wrl[il],    b0);
        b1=fmaf(Ln, wrl[16+il], b1);
        b2=fmaf(Ln, wrl[32+il], b2);
        b3=fmaf(Ln, wrl[48+il], b3);
      }
      __syncthreads();
      if (tid < 64){
        int r = tid>>4, il = tid&15;
        float sm = fpart[r*16+il] + fpart[64+r*16+il] + fpart[128+r*16+il] + fpart[192+r*16+il];
        st_agt(wsb+bFWD + ((size_t)r<<8) + ri + il, sm);
      }
      float* slot = wsb + bBWDP + (size_t)(ci&3)*1024;   // 4-way contention only
      atomicAdd(&slot[j], b0);      atomicAdd(&slot[256+j], b1);
      atomicAdd(&slot[512+j], b2);  atomicAdd(&slot[768+j], b3);
      // mem update rows ri..ri+15
      {
        const int half = lane>>5, l32 = lane&31;
        int row2 = tid>>5, c2 = tid&31;
        float2 er  = ld2_agt(wsb+bERS + (c2<<1));
        float2 wv2 = ld2_agt(wsb+bWVC + (c2<<1));
        #pragma unroll
        for (int it=0; it<2; ++it){
          int row = ri + row2 + it*8;
          float wwn = wwl[row];
          float2 v = ld2_agt(wsb+bMEM + ((size_t)row<<6) + (c2<<1));
          v.x = v.x*(1.f - wwn*er.x) + wwn*wv2.x;
          v.y = v.y*(1.f - wwn*er.y) + wwn*wv2.y;
          st2_agt(wsb+bMEM + ((size_t)row<<6) + (c2<<1), v);
          float s2 = hredsum32(v.x*v.x + v.y*v.y);
          if (c2==0) st_agt(wsb+bNRM+row, s2);
        }
        (void)half; (void)l32;
      }
    }
    ep++; cbar(wsb, ep, ci);

    // ================= E: read heads (ci<4: head r=ci) =================
    if (ci < 4){
      int r = ci;
      float* knl=smem; float* sims=smem+64; float* wrs=smem+320;
      float* part=smem+576; float* red=smem+832;
      if (wv==0) knl[lane]=ld_agt(wsb+bKNR+(r<<6)+lane);
      __syncthreads();
      const float* memb = wsb + bMEM;
      {
        int row2 = tid>>5, c2 = tid&31;
        for (int it=0; it<32; ++it){
          int n = row2 + it*8;
          float2 v = ld2_agt(memb + ((size_t)n<<6) + (c2<<1));
          float d = hredsum32(v.x*knl[c2<<1] + v.y*knl[(c2<<1)+1]);
          if (c2==0) sims[n] = d/(sqrtf(ld_agt(wsb+bNRM+n))+1e-6f);
        }
      }
      __syncthreads();
      float sv=sims[tid];
      float mx=bredmax(sv,red); float e=expf(sv-mx); float sm=bredsum(e,red);
      float cr=e/sm;
      float p0=ld_agt(wsb+bPI+r*3), p1=ld_agt(wsb+bPI+r*3+1), p2=ld_agt(wsb+bPI+r*3+2);
      float bwv = ld_agt(wsb+bBWDP + ((size_t)r<<8) + tid)
                + ld_agt(wsb+bBWDP + 1024 + ((size_t)r<<8) + tid)
                + ld_agt(wsb+bBWDP + 2048 + ((size_t)r<<8) + tid)
                + ld_agt(wsb+bBWDP + 3072 + ((size_t)r<<8) + tid);
      float wr = p0*bwv + p1*cr + p2*ld_agt(wsb+bFWD+((size_t)r<<8)+tid);
      st_agt(wsb+bWR+((size_t)r<<8)+tid, wr);
      wrs[tid]=wr;
      __syncthreads();
      {
        int m = tid&63, ksn = tid>>6;
        float a=0.f;
        #pragma unroll 8
        for (int n0=0;n0<64;++n0){
          int n = (ksn<<6)+n0;
          a = fmaf(wrs[n], ld_agt(memb + ((size_t)n<<6) + m), a);
        }
        part[(ksn<<6)+m]=a;
      }
      __syncthreads();
      if (tid<64)
        st_sys(wsb+bRV+(r<<6)+tid, part[tid]+part[64+tid]+part[128+tid]+part[192+tid]);
    }
    ep++; cbar(wsb, ep, ci);

    // state flag: rv(t) complete and sys-visible (cbar drained stores)
    if (ci==0 && tid==0)
      __hip_atomic_store((unsigned*)(wsb + bSTF), (unsigned)(t+1),
                         __ATOMIC_RELAXED, __HIP_MEMORY_SCOPE_SYSTEM);
  }

  // ---- epilogue: y(255) = YH + rv(255) @ Wr ----
  {
    float* srv  = smem;        // 256
    float* ysum = smem + 256;  // 256
    for (int e=tid;e<256;e+=NT) srv[e]=ld_sys(wsb+bRV+e);
    __syncthreads();
    int ks2 = tid>>4, cc = tid&15;
    int yc = (ci<<4) + cc;
    float a = 0.f;
    const float* wp = Wr + (size_t)(ks2*16)*256 + yc;
    const float* rp = srv + ks2*16;
    #pragma unroll
    for (int k=0;k<16;++k) a = fmaf(rp[k], wp[(size_t)k*256], a);
    ysum[ks2*16 + cc] = a;
    __syncthreads();
    if (tid < 16){
      float sm = 0.f;
      #pragma unroll
      for (int p=0;p<16;++p) sm += ysum[p*16 + tid];
      int yc2 = (ci<<4) + tid;
      out[((size_t)(b*256 + 255))*256 + yc2] = ld_agt(wsb+bYH+yc2) + sm;
    }
  }
}

extern "C" void kernel_launch(void* const* d_in, const int* in_sizes, int n_in,
                              void* d_out, int out_size, void* d_ws, size_t ws_size,
                              hipStream_t stream) {
  (void)in_sizes; (void)out_size;
  if (n_in < 9) return;
  const float* xin = (const float*)d_in[0];
  const float* Wx  = (const float*)d_in[1];
  const float* Wh  = (const float*)d_in[2];
  const float* bl  = (const float*)d_in[3];
  const float* Wxi = (const float*)d_in[4];
  const float* bxi = (const float*)d_in[5];
  const float* Wy  = (const float*)d_in[6];
  const float* Wr  = (const float*)d_in[7];
  const float* by  = (const float*)d_in[8];
  float* out = (float*)d_out;
  float* ws  = (float*)d_ws;
  if (ws_size < WS_TOTAL*sizeof(float)) return;

  hipLaunchKernelGGL(k_zero, dim3(512), dim3(256), 0, stream, ws);
  hipLaunchKernelGGL(k_dnc, dim3(NB), dim3(NT), 0, stream,
                     xin, Wx, Wh, bl, Wxi, bxi, Wy, Wr, by, out, ws);
}